// Round 1
// baseline (3638.529 us; speedup 1.0000x reference)
//
#include <hip/hip_runtime.h>
#include <hip/hip_bf16.h>
#include <math.h>

// Problem constants
#define Bz 4
#define Sz 512
#define Dz 2048
#define NHz 8
#define DEGz 4
#define HDz 256
#define AHz 16
#define AHDz 128
#define SCALE_ATT 0.08838834764831845f  // 1/sqrt(128)

// ---------------------------------------------------------------------------
// rmsnorm over last dim (D=2048), one block per row, 256 threads
__global__ __launch_bounds__(256) void rmsnorm_kernel(const float* __restrict__ x,
                                                      const float* __restrict__ w,
                                                      float* __restrict__ out) {
    long long base = (long long)blockIdx.x * Dz;
    int t = threadIdx.x;
    float v[8];
    float ss = 0.f;
#pragma unroll
    for (int p = 0; p < 8; ++p) { v[p] = x[base + t + p * 256]; ss += v[p] * v[p]; }
    __shared__ float red[256];
    red[t] = ss; __syncthreads();
    for (int s2 = 128; s2 > 0; s2 >>= 1) { if (t < s2) red[t] += red[t + s2]; __syncthreads(); }
    float sc = rsqrtf(red[0] / (float)Dz + 1e-6f);
#pragma unroll
    for (int p = 0; p < 8; ++p) { int c = t + p * 256; out[base + c] = v[p] * sc * w[c]; }
}

// x_mean[b,d] = mean_s xn[b,s,d]; one thread per (b,d)
__global__ __launch_bounds__(256) void xmean_kernel(const float* __restrict__ xn,
                                                    float* __restrict__ xm) {
    int idx = blockIdx.x * 256 + threadIdx.x;   // [0, B*D)
    int b = idx >> 11;
    int d = idx & (Dz - 1);
    const float* p = xn + (long long)b * Sz * Dz + d;
    float s = 0.f;
    for (int si = 0; si < Sz; ++si) s += p[(long long)si * Dz];
    xm[idx] = s * (1.0f / (float)Sz);
}

// h[b,j] = silu(x_mean[b,:] @ wc1[:,j] + bc1[j]); one thread per (b,j), j<512
__global__ __launch_bounds__(256) void mlp1_kernel(const float* __restrict__ xm,
                                                   const float* __restrict__ wc1,
                                                   const float* __restrict__ bc1,
                                                   float* __restrict__ h) {
    int idx = blockIdx.x * 256 + threadIdx.x;   // [0, B*512)
    int b = idx >> 9;
    int j = idx & 511;
    float s = bc1[j];
    const float* xb = xm + b * Dz;
    for (int k = 0; k < Dz; ++k) s += xb[k] * wc1[(long long)k * 512 + j];
    h[idx] = s / (1.0f + expf(-s));
}

// coeffs[b,i] = (h[b,:] @ wc2[:,i] + bc2[i]) * 0.1/(k+1), i in [0,8192)
__global__ __launch_bounds__(256) void coeffs_kernel(const float* __restrict__ h,
                                                     const float* __restrict__ wc2,
                                                     const float* __restrict__ bc2,
                                                     float* __restrict__ coeffs) {
    int idx = blockIdx.x * 256 + threadIdx.x;   // [0, B*8192)
    int b = idx >> 13;
    int i = idx & 8191;
    float s = bc2[i];
    const float* hb = h + b * 512;
    for (int k = 0; k < 512; ++k) s += hb[k] * wc2[(long long)k * 8192 + i];
    int kdeg = (i >> 8) & 3;
    s *= 0.1f / (float)(kdeg + 1);
    coeffs[idx] = s;
}

// Chebyshev path: z=tanh(head-mean), T0..T3, cheby_out = sum_k T_k * coeffs,
// kv_src = xn + cheby_out. One block per (b,s).
__global__ __launch_bounds__(256) void cheby_kernel(const float* __restrict__ xn,
                                                    const float* __restrict__ coeffs,
                                                    float* __restrict__ cheby_out,
                                                    float* __restrict__ kv_src) {
    int bs = blockIdx.x;               // b*S + s
    int b = bs >> 9;
    long long base = (long long)bs * Dz;
    int t = threadIdx.x;
    __shared__ float xrow[Dz];
    __shared__ float hsum[NHz][33];
    __shared__ float T[NHz][4];
#pragma unroll
    for (int p = 0; p < 8; ++p) xrow[t + p * 256] = xn[base + t + p * 256];
    __syncthreads();
    int hh = t >> 5, lane = t & 31;
    float s = 0.f;
#pragma unroll
    for (int q = 0; q < 8; ++q) s += xrow[hh * HDz + lane + q * 32];
    hsum[hh][lane] = s;
    __syncthreads();
    if (t < NHz) {
        float tot = 0.f;
        for (int l = 0; l < 32; ++l) tot += hsum[t][l];
        float z = tanhf(tot / (float)HDz);
        float t2 = 2.f * z * z - 1.f;
        T[t][0] = 1.f; T[t][1] = z; T[t][2] = t2; T[t][3] = 2.f * z * t2 - z;
    }
    __syncthreads();
    const float* cb = coeffs + (long long)b * (NHz * DEGz * HDz);
#pragma unroll
    for (int p = 0; p < 8; ++p) {
        int e = t + p * 256;
        int hd = e >> 8;               // head index == p
        int d = e & (HDz - 1);
        const float* ch = cb + hd * (DEGz * HDz) + d;
        float co = T[hd][0] * ch[0] + T[hd][1] * ch[HDz] + T[hd][2] * ch[2 * HDz] + T[hd][3] * ch[3 * HDz];
        cheby_out[base + e] = co;
        kv_src[base + e] = xrow[e] + co;
    }
}

// ---------------------------------------------------------------------------
// Generic batched fp32 GEMM: C = A @ B (+ addsrc), 64x64 tile, KT=16.
// Batch index z decomposed: zb = z/nbh, zh = z%nbh; offsets via strides.
// transB: B is (N x K) row-major, use B[n*ldb + k].
#define GT 64
#define GKT 16
__global__ __launch_bounds__(256) void gemm_kernel(const float* __restrict__ A,
                                                   const float* __restrict__ B,
                                                   float* __restrict__ C,
                                                   const float* __restrict__ addsrc,
                                                   int K, int lda, int ldb, int ldc,
                                                   int nbh,
                                                   long long sAb, long long sAh,
                                                   long long sBb, long long sBh,
                                                   long long sCb, long long sCh,
                                                   int transB) {
    int z = blockIdx.z;
    int zb = z / nbh, zh = z % nbh;
    const float* Ab = A + zb * sAb + zh * sAh;
    const float* Bb = B + zb * sBb + zh * sBh;
    float* Cb = C + zb * sCb + zh * sCh;

    __shared__ float As[GKT][GT + 1];
    __shared__ float Bs[GKT][GT + 1];

    int t = threadIdx.x;
    int tx = t & 15, ty = t >> 4;
    int row0 = blockIdx.y * GT;
    int col0 = blockIdx.x * GT;

    float acc[4][4] = {};

    for (int k0 = 0; k0 < K; k0 += GKT) {
        {
            int kk = t & 15;
            int rb = t >> 4;
#pragma unroll
            for (int p = 0; p < 4; ++p) {
                int r = rb + p * 16;
                As[kk][r] = Ab[(long long)(row0 + r) * lda + (k0 + kk)];
            }
        }
        if (!transB) {
            int nn = t & 63;
            int kb = t >> 6;
#pragma unroll
            for (int p = 0; p < 4; ++p) {
                int kk = kb + p * 4;
                Bs[kk][nn] = Bb[(long long)(k0 + kk) * ldb + (col0 + nn)];
            }
        } else {
            int kk = t & 15;
            int nb = t >> 4;
#pragma unroll
            for (int p = 0; p < 4; ++p) {
                int nn = nb + p * 16;
                Bs[kk][nn] = Bb[(long long)(col0 + nn) * ldb + (k0 + kk)];
            }
        }
        __syncthreads();
#pragma unroll
        for (int kk = 0; kk < GKT; ++kk) {
            float a[4], bv[4];
#pragma unroll
            for (int i = 0; i < 4; ++i) a[i] = As[kk][ty * 4 + i];
#pragma unroll
            for (int j = 0; j < 4; ++j) bv[j] = Bs[kk][tx * 4 + j];
#pragma unroll
            for (int i = 0; i < 4; ++i)
#pragma unroll
                for (int j = 0; j < 4; ++j) acc[i][j] += a[i] * bv[j];
        }
        __syncthreads();
    }
#pragma unroll
    for (int i = 0; i < 4; ++i) {
        int r = row0 + ty * 4 + i;
#pragma unroll
        for (int j = 0; j < 4; ++j) {
            int c = col0 + tx * 4 + j;
            float v = acc[i][j];
            if (addsrc) v += addsrc[zb * sCb + zh * sCh + (long long)r * ldc + c];
            Cb[(long long)r * ldc + c] = v;
        }
    }
}

// ---------------------------------------------------------------------------
// Causal softmax over 512-wide score rows. Block per row (b,h,i), 128 threads.
__global__ __launch_bounds__(128) void softmax_kernel(float* __restrict__ scores) {
    long long rid = blockIdx.x;              // (b*AH + h)*S + i
    int i = (int)(rid & (Sz - 1));
    float* row = scores + rid * Sz;
    int t = threadIdx.x;
    float vals[4];
    float mx = -1e30f;
#pragma unroll
    for (int p = 0; p < 4; ++p) {
        int j = t + p * 128;
        float v = row[j] * SCALE_ATT;
        if (j > i) v = -1e9f;
        vals[p] = v;
        mx = fmaxf(mx, v);
    }
    __shared__ float red[128];
    red[t] = mx; __syncthreads();
    for (int s2 = 64; s2 > 0; s2 >>= 1) { if (t < s2) red[t] = fmaxf(red[t], red[t + s2]); __syncthreads(); }
    mx = red[0]; __syncthreads();
    float sum = 0.f;
#pragma unroll
    for (int p = 0; p < 4; ++p) { vals[p] = expf(vals[p] - mx); sum += vals[p]; }
    red[t] = sum; __syncthreads();
    for (int s2 = 64; s2 > 0; s2 >>= 1) { if (t < s2) red[t] += red[t + s2]; __syncthreads(); }
    float inv = 1.0f / red[0];
#pragma unroll
    for (int p = 0; p < 4; ++p) row[t + p * 128] = vals[p] * inv;
}

// ---------------------------------------------------------------------------
// hcat = [rmsnorm(cheby,w_nc), rmsnorm(slr,w_ns)] ; block per row
__global__ __launch_bounds__(256) void hcat_kernel(const float* __restrict__ cheby,
                                                   const float* __restrict__ slr,
                                                   const float* __restrict__ w_nc,
                                                   const float* __restrict__ w_ns,
                                                   float* __restrict__ hcat) {
    long long row = blockIdx.x;
    const float* c = cheby + row * Dz;
    const float* sl = slr + row * Dz;
    float* o = hcat + row * (2 * Dz);
    int t = threadIdx.x;
    float v1[8], v2[8];
    float ss1 = 0.f, ss2 = 0.f;
#pragma unroll
    for (int p = 0; p < 8; ++p) {
        v1[p] = c[t + p * 256];  ss1 += v1[p] * v1[p];
        v2[p] = sl[t + p * 256]; ss2 += v2[p] * v2[p];
    }
    __shared__ float red[256];
    red[t] = ss1; __syncthreads();
    for (int s2 = 128; s2 > 0; s2 >>= 1) { if (t < s2) red[t] += red[t + s2]; __syncthreads(); }
    float sc1 = rsqrtf(red[0] / (float)Dz + 1e-6f);
    __syncthreads();
    red[t] = ss2; __syncthreads();
    for (int s2 = 128; s2 > 0; s2 >>= 1) { if (t < s2) red[t] += red[t + s2]; __syncthreads(); }
    float sc2 = rsqrtf(red[0] / (float)Dz + 1e-6f);
#pragma unroll
    for (int p = 0; p < 8; ++p) {
        int cx = t + p * 256;
        o[cx] = v1[p] * sc1 * w_nc[cx];
        o[Dz + cx] = v2[p] * sc2 * w_ns[cx];
    }
}

// fused = rmsnorm(silu(gate)*value, w_np); gv row = [gate(2048), value(2048)]
__global__ __launch_bounds__(256) void fusedgate_kernel(const float* __restrict__ gv,
                                                        const float* __restrict__ w_np,
                                                        float* __restrict__ fused) {
    long long row = blockIdx.x;
    const float* g = gv + row * (2 * Dz);
    float* o = fused + row * Dz;
    int t = threadIdx.x;
    float f[8];
    float ss = 0.f;
#pragma unroll
    for (int p = 0; p < 8; ++p) {
        float ga = g[t + p * 256];
        float va = g[Dz + t + p * 256];
        float sv = ga / (1.0f + expf(-ga)) * va;
        f[p] = sv; ss += sv * sv;
    }
    __shared__ float red[256];
    red[t] = ss; __syncthreads();
    for (int s2 = 128; s2 > 0; s2 >>= 1) { if (t < s2) red[t] += red[t + s2]; __syncthreads(); }
    float sc = rsqrtf(red[0] / (float)Dz + 1e-6f);
#pragma unroll
    for (int p = 0; p < 8; ++p) { int cx = t + p * 256; o[cx] = f[p] * sc * w_np[cx]; }
}

// ---------------------------------------------------------------------------
extern "C" void kernel_launch(void* const* d_in, const int* in_sizes, int n_in,
                              void* d_out, int out_size, void* d_ws, size_t ws_size,
                              hipStream_t stream) {
    const float* x     = (const float*)d_in[0];
    const float* w_in  = (const float*)d_in[1];
    // d_in[2..5]: wg1,bg1,wg2,bg2 -> dead code (gate path unused in output)
    const float* wc1   = (const float*)d_in[6];
    const float* bc1   = (const float*)d_in[7];
    const float* wc2   = (const float*)d_in[8];
    const float* bc2   = (const float*)d_in[9];
    const float* wq    = (const float*)d_in[10];
    const float* wk    = (const float*)d_in[11];
    const float* wv    = (const float*)d_in[12];
    const float* wo    = (const float*)d_in[13];
    const float* w_nc  = (const float*)d_in[14];
    const float* w_ns  = (const float*)d_in[15];
    const float* w_fgv = (const float*)d_in[16];
    const float* w_np  = (const float*)d_in[17];
    const float* w_out = (const float*)d_in[18];
    float* out = (float*)d_out;

    float* ws = (float*)d_ws;
    const long long U = (long long)Bz * Sz * Dz;     // 4M floats
    float* xn     = ws + 0 * U;   // later reused for k, then fused
    float* cheby  = ws + 1 * U;
    float* kv     = ws + 2 * U;   // later reused for o
    float* qb     = ws + 3 * U;   // later reused for slr
    float* vb     = ws + 4 * U;
    float* scores = ws + 5 * U;   // 16M floats [5U, 9U); later hcat [5U,7U) + gv [7U,9U)
    float* smalls = ws + 9 * U;
    float* xm     = smalls;                 // B*D = 8192
    float* hbuf   = smalls + 8192;          // B*512 = 2048
    float* cbuf   = smalls + 8192 + 2048;   // B*8192 = 32768

    float* kb    = xn;            // reuse
    float* ob    = kv;            // reuse
    float* slr   = qb;            // reuse
    float* hcat  = scores;        // 8M floats
    float* gvb   = scores + 2 * U;// 8M floats
    float* fused = xn;            // reuse (k dead by then)

    const int BS = Bz * Sz;       // 2048 rows

    // 1. xn = rmsnorm(x, w_in)
    hipLaunchKernelGGL(rmsnorm_kernel, dim3(BS), dim3(256), 0, stream, x, w_in, xn);
    // 2. x_mean
    hipLaunchKernelGGL(xmean_kernel, dim3(Bz * Dz / 256), dim3(256), 0, stream, xn, xm);
    // 3. h = silu(x_mean@wc1+bc1)
    hipLaunchKernelGGL(mlp1_kernel, dim3(Bz * 512 / 256), dim3(256), 0, stream, xm, wc1, bc1, hbuf);
    // 4. coeffs
    hipLaunchKernelGGL(coeffs_kernel, dim3(Bz * 8192 / 256), dim3(256), 0, stream, hbuf, wc2, bc2, cbuf);
    // 5. cheby_out + kv_src
    hipLaunchKernelGGL(cheby_kernel, dim3(BS), dim3(256), 0, stream, xn, cbuf, cheby, kv);
    // 6. q = xn @ wq      (2048 x 2048 x 2048)
    hipLaunchKernelGGL(gemm_kernel, dim3(Dz / GT, BS / GT, 1), dim3(256), 0, stream,
                       xn, wq, qb, (const float*)nullptr, Dz, Dz, Dz, Dz,
                       1, 0LL, 0LL, 0LL, 0LL, 0LL, 0LL, 0);
    // 7. k = kv @ wk  (into xn buffer)
    hipLaunchKernelGGL(gemm_kernel, dim3(Dz / GT, BS / GT, 1), dim3(256), 0, stream,
                       kv, wk, kb, (const float*)nullptr, Dz, Dz, Dz, Dz,
                       1, 0LL, 0LL, 0LL, 0LL, 0LL, 0LL, 0);
    // 8. v = kv @ wv
    hipLaunchKernelGGL(gemm_kernel, dim3(Dz / GT, BS / GT, 1), dim3(256), 0, stream,
                       kv, wv, vb, (const float*)nullptr, Dz, Dz, Dz, Dz,
                       1, 0LL, 0LL, 0LL, 0LL, 0LL, 0LL, 0);
    // 9. scores[bh] = q[bh] @ k[bh]^T   (batch 64: b stride S*D, h stride 128)
    hipLaunchKernelGGL(gemm_kernel, dim3(Sz / GT, Sz / GT, Bz * AHz), dim3(256), 0, stream,
                       qb, kb, scores, (const float*)nullptr, AHDz, Dz, Dz, Sz,
                       AHz,
                       (long long)Sz * Dz, (long long)AHDz,
                       (long long)Sz * Dz, (long long)AHDz,
                       (long long)AHz * Sz * Sz, (long long)Sz * Sz, 1);
    // 10. causal softmax (applies 1/sqrt(128) scaling)
    hipLaunchKernelGGL(softmax_kernel, dim3(Bz * AHz * Sz), dim3(128), 0, stream, scores);
    // 11. o[bh] = attn[bh] @ v[bh]   (M=512, N=128, K=512)
    hipLaunchKernelGGL(gemm_kernel, dim3(AHDz / GT, Sz / GT, Bz * AHz), dim3(256), 0, stream,
                       scores, vb, ob, (const float*)nullptr, Sz, Sz, Dz, Dz,
                       AHz,
                       (long long)AHz * Sz * Sz, (long long)Sz * Sz,
                       (long long)Sz * Dz, (long long)AHDz,
                       (long long)Sz * Dz, (long long)AHDz, 0);
    // 12. slr = o @ wo
    hipLaunchKernelGGL(gemm_kernel, dim3(Dz / GT, BS / GT, 1), dim3(256), 0, stream,
                       ob, wo, slr, (const float*)nullptr, Dz, Dz, Dz, Dz,
                       1, 0LL, 0LL, 0LL, 0LL, 0LL, 0LL, 0);
    // 13. hcat = [rmsnorm(cheby,w_nc), rmsnorm(slr,w_ns)]
    hipLaunchKernelGGL(hcat_kernel, dim3(BS), dim3(256), 0, stream, cheby, slr, w_nc, w_ns, hcat);
    // 14. gv = hcat @ w_fgv  (2048 x 4096 x 4096)
    hipLaunchKernelGGL(gemm_kernel, dim3(2 * Dz / GT, BS / GT, 1), dim3(256), 0, stream,
                       hcat, w_fgv, gvb, (const float*)nullptr, 2 * Dz, 2 * Dz, 2 * Dz, 2 * Dz,
                       1, 0LL, 0LL, 0LL, 0LL, 0LL, 0LL, 0);
    // 15. fused = rmsnorm(silu(gate)*value, w_np)
    hipLaunchKernelGGL(fusedgate_kernel, dim3(BS), dim3(256), 0, stream, gvb, w_np, fused);
    // 16. out = x + fused @ w_out
    hipLaunchKernelGGL(gemm_kernel, dim3(Dz / GT, BS / GT, 1), dim3(256), 0, stream,
                       fused, w_out, out, x, Dz, Dz, Dz, Dz,
                       1, 0LL, 0LL, 0LL, 0LL, 0LL, 0LL, 0);
}

// Round 2
// 807.924 us; speedup vs baseline: 4.5036x; 4.5036x over previous
//
#include <hip/hip_runtime.h>
#include <hip/hip_bf16.h>
#include <math.h>

#define Bz 4
#define Sz 512
#define Dz 2048
#define NHz 8
#define DEGz 4
#define HDz 256
#define AHz 16
#define AHDz 128
#define SCALE_ATT 0.08838834764831845f  // 1/sqrt(128)

typedef __attribute__((ext_vector_type(8))) short short8;
typedef __attribute__((ext_vector_type(4))) float f32x4;

#define AS1 __attribute__((address_space(1)))
#define AS3 __attribute__((address_space(3)))

__device__ inline void gload16(const void* g, void* l) {
    __builtin_amdgcn_global_load_lds((const AS1 void*)g, (AS3 void*)l, 16, 0, 0);
}

// ---------------------------------------------------------------------------
// bf16 MFMA GEMM (m97 structure): C[m][n] = sum_k A[m][k] * BT[n][k]
// 128x128 tile, BK=32, 256 threads = 4 waves, each wave 64x64 via 4x4 MFMAs.
// flags: 1 = bf16 out, 2 = fp32 residual add, 4 = score epilogue (scale+mask)
__global__ __launch_bounds__(256) void gemm_bt(
    const unsigned short* __restrict__ A,   // M x K bf16, lda
    const unsigned short* __restrict__ B,   // N x K bf16, ldb (B-transposed form)
    void* __restrict__ Cout,
    const float* __restrict__ addsrc,
    int K, int lda, int ldb, int ldc, int nbh,
    long long sAb, long long sAh,
    long long sBb, long long sBh,
    long long sCb, long long sCh,
    int flags)
{
    __shared__ unsigned short As[128 * 32];
    __shared__ unsigned short Bs[128 * 32];

    int z = blockIdx.z;
    int zb = z / nbh, zh = z - zb * nbh;
    int row0 = blockIdx.y * 128, col0 = blockIdx.x * 128;
    long long cb = zb * sCb + zh * sCh;
    int t = threadIdx.x;

    if ((flags & 4) && (col0 > row0 + 127)) {
        // fully-masked score tile: write -1e9 and exit
        __hip_bfloat16* C = (__hip_bfloat16*)Cout;
        __hip_bfloat16 neg = __float2bfloat16(-1e9f);
#pragma unroll 4
        for (int p = 0; p < 64; ++p) {
            int idx = p * 256 + t;
            int r = idx >> 7, c = idx & 127;
            C[cb + (long long)(row0 + r) * ldc + (col0 + c)] = neg;
        }
        return;
    }

    const unsigned short* Ab = A + zb * sAb + zh * sAh;
    const unsigned short* Bb = B + zb * sBb + zh * sBh;

    int w = t >> 6, l = t & 63;
    int lrow = l >> 2;            // row within 16-row segment
    int lchunk = (l & 3) * 8;     // k-element offset of 8-elem chunk

    const unsigned short* aP0 = Ab + (long long)(row0 + w * 16 + lrow) * lda + lchunk;
    const unsigned short* aP1 = aP0 + 64LL * lda;
    const unsigned short* bP0 = Bb + (long long)(col0 + w * 16 + lrow) * ldb + lchunk;
    const unsigned short* bP1 = bP0 + 64LL * ldb;
    unsigned short* aL0 = As + w * 512;
    unsigned short* aL1 = As + (w + 4) * 512;
    unsigned short* bL0 = Bs + w * 512;
    unsigned short* bL1 = Bs + (w + 4) * 512;

    int lm = l & 15, lq = l >> 4;
    int wr = (w >> 1) * 64, wc = (w & 1) * 64;

    f32x4 acc[4][4];
#pragma unroll
    for (int i = 0; i < 4; ++i)
#pragma unroll
        for (int j = 0; j < 4; ++j) acc[i][j] = (f32x4){0.f, 0.f, 0.f, 0.f};

    for (int k0 = 0; k0 < K; k0 += 32) {
        gload16(aP0, aL0);
        gload16(aP1, aL1);
        gload16(bP0, bL0);
        gload16(bP1, bL1);
        aP0 += 32; aP1 += 32; bP0 += 32; bP1 += 32;
        __syncthreads();

        short8 af[4], bfr[4];
#pragma unroll
        for (int i = 0; i < 4; ++i)
            af[i] = *(const short8*)(As + (wr + i * 16 + lm) * 32 + lq * 8);
#pragma unroll
        for (int j = 0; j < 4; ++j)
            bfr[j] = *(const short8*)(Bs + (wc + j * 16 + lm) * 32 + lq * 8);
#pragma unroll
        for (int i = 0; i < 4; ++i)
#pragma unroll
            for (int j = 0; j < 4; ++j)
                acc[i][j] = __builtin_amdgcn_mfma_f32_16x16x32_bf16(af[i], bfr[j], acc[i][j], 0, 0, 0);
        __syncthreads();
    }

    // epilogue: C/D layout col=lane&15, row=(lane>>4)*4+reg
    if (flags & 1) {
        __hip_bfloat16* C = (__hip_bfloat16*)Cout;
#pragma unroll
        for (int i = 0; i < 4; ++i)
#pragma unroll
            for (int j = 0; j < 4; ++j)
#pragma unroll
                for (int r = 0; r < 4; ++r) {
                    int grow = row0 + wr + i * 16 + lq * 4 + r;
                    int gcol = col0 + wc + j * 16 + lm;
                    float v = acc[i][j][r];
                    if (flags & 4) v = (gcol > grow) ? -1e9f : v * SCALE_ATT;
                    C[cb + (long long)grow * ldc + gcol] = __float2bfloat16(v);
                }
    } else {
        float* C = (float*)Cout;
#pragma unroll
        for (int i = 0; i < 4; ++i)
#pragma unroll
            for (int j = 0; j < 4; ++j)
#pragma unroll
                for (int r = 0; r < 4; ++r) {
                    int grow = row0 + wr + i * 16 + lq * 4 + r;
                    int gcol = col0 + wc + j * 16 + lm;
                    float v = acc[i][j][r];
                    long long ci = cb + (long long)grow * ldc + gcol;
                    if (flags & 2) v += addsrc[ci];
                    C[ci] = v;
                }
    }
}

// ---------------------------------------------------------------------------
// transpose + fp32->bf16: out[n][k] = bf16(in[k][n]); in is Kd x Nd
__global__ __launch_bounds__(256) void transpose_cvt(const float* __restrict__ in,
                                                     __hip_bfloat16* __restrict__ out,
                                                     int Kd, int Nd) {
    __shared__ float tile[32][33];
    int n0 = blockIdx.x * 32, k0 = blockIdx.y * 32;
    int t = threadIdx.x;
    int c = t & 31, r8 = t >> 5;   // 8 rows x 32 cols
#pragma unroll
    for (int p = 0; p < 4; ++p)
        tile[r8 + p * 8][c] = in[(long long)(k0 + r8 + p * 8) * Nd + n0 + c];
    __syncthreads();
#pragma unroll
    for (int p = 0; p < 4; ++p)
        out[(long long)(n0 + r8 + p * 8) * Kd + k0 + c] = __float2bfloat16(tile[c][r8 + p * 8]);
}

// ---------------------------------------------------------------------------
// rmsnorm (fp32 in, bf16 out), one block per row
__global__ __launch_bounds__(256) void rmsnorm_kernel(const float* __restrict__ x,
                                                      const float* __restrict__ w,
                                                      __hip_bfloat16* __restrict__ out) {
    long long base = (long long)blockIdx.x * Dz;
    int t = threadIdx.x;
    float v[8];
    float ss = 0.f;
#pragma unroll
    for (int p = 0; p < 8; ++p) { v[p] = x[base + t + p * 256]; ss += v[p] * v[p]; }
    __shared__ float red[256];
    red[t] = ss; __syncthreads();
    for (int s2 = 128; s2 > 0; s2 >>= 1) { if (t < s2) red[t] += red[t + s2]; __syncthreads(); }
    float sc = rsqrtf(red[0] / (float)Dz + 1e-6f);
#pragma unroll
    for (int p = 0; p < 8; ++p) { int c = t + p * 256; out[base + c] = __float2bfloat16(v[p] * sc * w[c]); }
}

__global__ __launch_bounds__(256) void xmean_kernel(const __hip_bfloat16* __restrict__ xn,
                                                    float* __restrict__ xm) {
    int idx = blockIdx.x * 256 + threadIdx.x;
    int b = idx >> 11;
    int d = idx & (Dz - 1);
    const __hip_bfloat16* p = xn + (long long)b * Sz * Dz + d;
    float s = 0.f;
    for (int si = 0; si < Sz; ++si) s += __bfloat162float(p[(long long)si * Dz]);
    xm[idx] = s * (1.0f / (float)Sz);
}

__global__ __launch_bounds__(256) void mlp1_kernel(const float* __restrict__ xm,
                                                   const float* __restrict__ wc1,
                                                   const float* __restrict__ bc1,
                                                   float* __restrict__ h) {
    int idx = blockIdx.x * 256 + threadIdx.x;
    int b = idx >> 9;
    int j = idx & 511;
    float s = bc1[j];
    const float* xb = xm + b * Dz;
    for (int k = 0; k < Dz; ++k) s += xb[k] * wc1[(long long)k * 512 + j];
    h[idx] = s / (1.0f + expf(-s));
}

__global__ __launch_bounds__(256) void coeffs_kernel(const float* __restrict__ h,
                                                     const float* __restrict__ wc2,
                                                     const float* __restrict__ bc2,
                                                     float* __restrict__ coeffs) {
    int idx = blockIdx.x * 256 + threadIdx.x;
    int b = idx >> 13;
    int i = idx & 8191;
    float s = bc2[i];
    const float* hb = h + b * 512;
    for (int k = 0; k < 512; ++k) s += hb[k] * wc2[(long long)k * 8192 + i];
    int kdeg = (i >> 8) & 3;
    s *= 0.1f / (float)(kdeg + 1);
    coeffs[idx] = s;
}

// Chebyshev path; xn bf16 in, cheby/kv bf16 out
__global__ __launch_bounds__(256) void cheby_kernel(const __hip_bfloat16* __restrict__ xn,
                                                    const float* __restrict__ coeffs,
                                                    __hip_bfloat16* __restrict__ cheby_out,
                                                    __hip_bfloat16* __restrict__ kv_src) {
    int bs = blockIdx.x;
    int b = bs >> 9;
    long long base = (long long)bs * Dz;
    int t = threadIdx.x;
    __shared__ float xrow[Dz];
    __shared__ float hsum[NHz][33];
    __shared__ float T[NHz][4];
#pragma unroll
    for (int p = 0; p < 8; ++p) xrow[t + p * 256] = __bfloat162float(xn[base + t + p * 256]);
    __syncthreads();
    int hh = t >> 5, lane = t & 31;
    float s = 0.f;
#pragma unroll
    for (int q = 0; q < 8; ++q) s += xrow[hh * HDz + lane + q * 32];
    hsum[hh][lane] = s;
    __syncthreads();
    if (t < NHz) {
        float tot = 0.f;
        for (int l2 = 0; l2 < 32; ++l2) tot += hsum[t][l2];
        float z = tanhf(tot / (float)HDz);
        float t2 = 2.f * z * z - 1.f;
        T[t][0] = 1.f; T[t][1] = z; T[t][2] = t2; T[t][3] = 2.f * z * t2 - z;
    }
    __syncthreads();
    const float* cbp = coeffs + (long long)b * (NHz * DEGz * HDz);
#pragma unroll
    for (int p = 0; p < 8; ++p) {
        int e = t + p * 256;
        int hd = e >> 8;
        int d = e & (HDz - 1);
        const float* ch = cbp + hd * (DEGz * HDz) + d;
        float co = T[hd][0] * ch[0] + T[hd][1] * ch[HDz] + T[hd][2] * ch[2 * HDz] + T[hd][3] * ch[3 * HDz];
        cheby_out[base + e] = __float2bfloat16(co);
        kv_src[base + e] = __float2bfloat16(xrow[e] + co);
    }
}

// softmax over 512-wide bf16 rows, in place (scale+mask already applied)
__global__ __launch_bounds__(128) void softmax_kernel(__hip_bfloat16* __restrict__ sc) {
    long long base = (long long)blockIdx.x * Sz;
    int t = threadIdx.x;
    float vals[4];
    float mx = -1e30f;
#pragma unroll
    for (int p = 0; p < 4; ++p) {
        float v = __bfloat162float(sc[base + t + p * 128]);
        vals[p] = v;
        mx = fmaxf(mx, v);
    }
    __shared__ float red[128];
    red[t] = mx; __syncthreads();
    for (int s2 = 64; s2 > 0; s2 >>= 1) { if (t < s2) red[t] = fmaxf(red[t], red[t + s2]); __syncthreads(); }
    mx = red[0]; __syncthreads();
    float sum = 0.f;
#pragma unroll
    for (int p = 0; p < 4; ++p) { vals[p] = __expf(vals[p] - mx); sum += vals[p]; }
    red[t] = sum; __syncthreads();
    for (int s2 = 64; s2 > 0; s2 >>= 1) { if (t < s2) red[t] += red[t + s2]; __syncthreads(); }
    float inv = 1.0f / red[0];
#pragma unroll
    for (int p = 0; p < 4; ++p) sc[base + t + p * 128] = __float2bfloat16(vals[p] * inv);
}

// hcat = [rmsnorm(cheby,w_nc), rmsnorm(slr,w_ns)], bf16 in/out
__global__ __launch_bounds__(256) void hcat_kernel(const __hip_bfloat16* __restrict__ cheby,
                                                   const __hip_bfloat16* __restrict__ slr,
                                                   const float* __restrict__ w_nc,
                                                   const float* __restrict__ w_ns,
                                                   __hip_bfloat16* __restrict__ hcat) {
    long long row = blockIdx.x;
    const __hip_bfloat16* c = cheby + row * Dz;
    const __hip_bfloat16* sl = slr + row * Dz;
    __hip_bfloat16* o = hcat + row * (2 * Dz);
    int t = threadIdx.x;
    float v1[8], v2[8];
    float ss1 = 0.f, ss2 = 0.f;
#pragma unroll
    for (int p = 0; p < 8; ++p) {
        v1[p] = __bfloat162float(c[t + p * 256]);  ss1 += v1[p] * v1[p];
        v2[p] = __bfloat162float(sl[t + p * 256]); ss2 += v2[p] * v2[p];
    }
    __shared__ float red[256];
    red[t] = ss1; __syncthreads();
    for (int s2 = 128; s2 > 0; s2 >>= 1) { if (t < s2) red[t] += red[t + s2]; __syncthreads(); }
    float sc1 = rsqrtf(red[0] / (float)Dz + 1e-6f);
    __syncthreads();
    red[t] = ss2; __syncthreads();
    for (int s2 = 128; s2 > 0; s2 >>= 1) { if (t < s2) red[t] += red[t + s2]; __syncthreads(); }
    float sc2 = rsqrtf(red[0] / (float)Dz + 1e-6f);
#pragma unroll
    for (int p = 0; p < 8; ++p) {
        int cx = t + p * 256;
        o[cx] = __float2bfloat16(v1[p] * sc1 * w_nc[cx]);
        o[Dz + cx] = __float2bfloat16(v2[p] * sc2 * w_ns[cx]);
    }
}

// fused = rmsnorm(silu(gate)*value, w_np); gv bf16 rows of 4096
__global__ __launch_bounds__(256) void fusedgate_kernel(const __hip_bfloat16* __restrict__ gv,
                                                        const float* __restrict__ w_np,
                                                        __hip_bfloat16* __restrict__ fused) {
    long long row = blockIdx.x;
    const __hip_bfloat16* g = gv + row * (2 * Dz);
    __hip_bfloat16* o = fused + row * Dz;
    int t = threadIdx.x;
    float f[8];
    float ss = 0.f;
#pragma unroll
    for (int p = 0; p < 8; ++p) {
        float ga = __bfloat162float(g[t + p * 256]);
        float va = __bfloat162float(g[Dz + t + p * 256]);
        float sv = ga / (1.0f + expf(-ga)) * va;
        f[p] = sv; ss += sv * sv;
    }
    __shared__ float red[256];
    red[t] = ss; __syncthreads();
    for (int s2 = 128; s2 > 0; s2 >>= 1) { if (t < s2) red[t] += red[t + s2]; __syncthreads(); }
    float sc = rsqrtf(red[0] / (float)Dz + 1e-6f);
#pragma unroll
    for (int p = 0; p < 8; ++p) { int cx = t + p * 256; o[cx] = __float2bfloat16(f[p] * sc * w_np[cx]); }
}

// ---------------------------------------------------------------------------
extern "C" void kernel_launch(void* const* d_in, const int* in_sizes, int n_in,
                              void* d_out, int out_size, void* d_ws, size_t ws_size,
                              hipStream_t stream) {
    const float* x     = (const float*)d_in[0];
    const float* w_in  = (const float*)d_in[1];
    const float* wc1   = (const float*)d_in[6];
    const float* bc1   = (const float*)d_in[7];
    const float* wc2   = (const float*)d_in[8];
    const float* bc2   = (const float*)d_in[9];
    const float* wq    = (const float*)d_in[10];
    const float* wk    = (const float*)d_in[11];
    const float* wv    = (const float*)d_in[12];
    const float* wo    = (const float*)d_in[13];
    const float* w_nc  = (const float*)d_in[14];
    const float* w_ns  = (const float*)d_in[15];
    const float* w_fgv = (const float*)d_in[16];
    const float* w_np  = (const float*)d_in[17];
    const float* w_out = (const float*)d_in[18];
    float* out = (float*)d_out;

    const size_t MB = 1ull << 20;
    char* W = (char*)d_ws;
    __hip_bfloat16* xn_bf    = (__hip_bfloat16*)(W + 0 * MB);
    __hip_bfloat16* kv_bf    = (__hip_bfloat16*)(W + 8 * MB);
    __hip_bfloat16* cheby_bf = (__hip_bfloat16*)(W + 16 * MB);
    __hip_bfloat16* q_bf     = (__hip_bfloat16*)(W + 24 * MB);
    __hip_bfloat16* k_bf     = (__hip_bfloat16*)(W + 32 * MB);
    __hip_bfloat16* vT_bf    = (__hip_bfloat16*)(W + 40 * MB);
    __hip_bfloat16* o_bf     = (__hip_bfloat16*)(W + 48 * MB);
    __hip_bfloat16* scores   = (__hip_bfloat16*)(W + 56 * MB);   // 32MB [56,88)
    __hip_bfloat16* wq_t     = (__hip_bfloat16*)(W + 88 * MB);
    __hip_bfloat16* wk_t     = (__hip_bfloat16*)(W + 96 * MB);
    __hip_bfloat16* wv_t     = (__hip_bfloat16*)(W + 104 * MB);
    __hip_bfloat16* wo_t     = (__hip_bfloat16*)(W + 112 * MB);
    __hip_bfloat16* wout_t   = (__hip_bfloat16*)(W + 120 * MB);
    // lifetime-based reuse
    __hip_bfloat16* wfgv_t   = (__hip_bfloat16*)(W + 56 * MB);   // after probs dead
    __hip_bfloat16* slr_bf   = (__hip_bfloat16*)(W + 0 * MB);    // xn dead
    __hip_bfloat16* hcat_bf  = (__hip_bfloat16*)(W + 24 * MB);   // q,k dead
    __hip_bfloat16* gv_bf    = (__hip_bfloat16*)(W + 40 * MB);   // vT,o dead
    __hip_bfloat16* fused_bf = (__hip_bfloat16*)(W + 8 * MB);    // kv dead
    float* xm   = (float*)(W + 128 * MB);
    float* hbuf = xm + 8192;
    float* cbuf = hbuf + 2048;

    const int BS = Bz * Sz;            // 2048
    const long long SD = (long long)Sz * Dz;
    const long long SS = (long long)Sz * Sz;

    // weight transposes (bf16), except wfgv (deferred to reuse scores region)
    hipLaunchKernelGGL(transpose_cvt, dim3(64, 64), dim3(256), 0, stream, wq, wq_t, Dz, Dz);
    hipLaunchKernelGGL(transpose_cvt, dim3(64, 64), dim3(256), 0, stream, wk, wk_t, Dz, Dz);
    hipLaunchKernelGGL(transpose_cvt, dim3(64, 64), dim3(256), 0, stream, wv, wv_t, Dz, Dz);
    hipLaunchKernelGGL(transpose_cvt, dim3(64, 64), dim3(256), 0, stream, wo, wo_t, Dz, Dz);
    hipLaunchKernelGGL(transpose_cvt, dim3(64, 64), dim3(256), 0, stream, w_out, wout_t, Dz, Dz);

    // 1. xn = rmsnorm(x)
    hipLaunchKernelGGL(rmsnorm_kernel, dim3(BS), dim3(256), 0, stream, x, w_in, xn_bf);
    // 2-4. coeff path
    hipLaunchKernelGGL(xmean_kernel, dim3(Bz * Dz / 256), dim3(256), 0, stream, xn_bf, xm);
    hipLaunchKernelGGL(mlp1_kernel, dim3(Bz * 512 / 256), dim3(256), 0, stream, xm, wc1, bc1, hbuf);
    hipLaunchKernelGGL(coeffs_kernel, dim3(Bz * 8192 / 256), dim3(256), 0, stream, hbuf, wc2, bc2, cbuf);
    // 5. cheby + kv_src
    hipLaunchKernelGGL(cheby_kernel, dim3(BS), dim3(256), 0, stream, xn_bf, cbuf, cheby_bf, kv_bf);
    // 6. q = xn @ wq
    hipLaunchKernelGGL(gemm_bt, dim3(16, 16, 1), dim3(256), 0, stream,
                       (const unsigned short*)xn_bf, (const unsigned short*)wq_t, (void*)q_bf,
                       (const float*)nullptr, Dz, Dz, Dz, Dz, 1,
                       0LL, 0LL, 0LL, 0LL, 0LL, 0LL, 1);
    // 7. k = kv @ wk
    hipLaunchKernelGGL(gemm_bt, dim3(16, 16, 1), dim3(256), 0, stream,
                       (const unsigned short*)kv_bf, (const unsigned short*)wk_t, (void*)k_bf,
                       (const float*)nullptr, Dz, Dz, Dz, Dz, 1,
                       0LL, 0LL, 0LL, 0LL, 0LL, 0LL, 1);
    // 8. vT_b = wv^T @ kv_b^T : A=wv_t (2048x2048), BT=kv_b (512x2048)
    hipLaunchKernelGGL(gemm_bt, dim3(4, 16, Bz), dim3(256), 0, stream,
                       (const unsigned short*)wv_t, (const unsigned short*)kv_bf, (void*)vT_bf,
                       (const float*)nullptr, Dz, Dz, Dz, Sz, 1,
                       0LL, 0LL, SD, 0LL, (long long)Dz * Sz, 0LL, 1);
    // 9. scores = q @ k^T with scale+causal, bf16 out
    hipLaunchKernelGGL(gemm_bt, dim3(4, 4, Bz * AHz), dim3(256), 0, stream,
                       (const unsigned short*)q_bf, (const unsigned short*)k_bf, (void*)scores,
                       (const float*)nullptr, AHDz, Dz, Dz, Sz, AHz,
                       SD, (long long)AHDz, SD, (long long)AHDz,
                       (long long)AHz * SS, SS, 1 | 4);
    // 10. softmax (in place, bf16)
    hipLaunchKernelGGL(softmax_kernel, dim3(Bz * AHz * Sz), dim3(128), 0, stream, scores);
    // 11. o = probs @ vT^T
    hipLaunchKernelGGL(gemm_bt, dim3(1, 4, Bz * AHz), dim3(256), 0, stream,
                       (const unsigned short*)scores, (const unsigned short*)vT_bf, (void*)o_bf,
                       (const float*)nullptr, Sz, Sz, Sz, Dz, AHz,
                       (long long)AHz * SS, SS,
                       (long long)Dz * Sz, (long long)AHDz * Sz,
                       SD, (long long)AHDz, 1);
    // 12. deferred w_fgv transpose into dead scores region
    hipLaunchKernelGGL(transpose_cvt, dim3(128, 128), dim3(256), 0, stream, w_fgv, wfgv_t, 2 * Dz, 2 * Dz);
    // 13. slr = o @ wo
    hipLaunchKernelGGL(gemm_bt, dim3(16, 16, 1), dim3(256), 0, stream,
                       (const unsigned short*)o_bf, (const unsigned short*)wo_t, (void*)slr_bf,
                       (const float*)nullptr, Dz, Dz, Dz, Dz, 1,
                       0LL, 0LL, 0LL, 0LL, 0LL, 0LL, 1);
    // 14. hcat
    hipLaunchKernelGGL(hcat_kernel, dim3(BS), dim3(256), 0, stream, cheby_bf, slr_bf, w_nc, w_ns, hcat_bf);
    // 15. gv = hcat @ w_fgv
    hipLaunchKernelGGL(gemm_bt, dim3(32, 16, 1), dim3(256), 0, stream,
                       (const unsigned short*)hcat_bf, (const unsigned short*)wfgv_t, (void*)gv_bf,
                       (const float*)nullptr, 2 * Dz, 2 * Dz, 2 * Dz, 2 * Dz, 1,
                       0LL, 0LL, 0LL, 0LL, 0LL, 0LL, 1);
    // 16. fused
    hipLaunchKernelGGL(fusedgate_kernel, dim3(BS), dim3(256), 0, stream, gv_bf, w_np, fused_bf);
    // 17. out = x + fused @ w_out (fp32 + residual)
    hipLaunchKernelGGL(gemm_bt, dim3(16, 16, 1), dim3(256), 0, stream,
                       (const unsigned short*)fused_bf, (const unsigned short*)wout_t, (void*)out,
                       x, Dz, Dz, Dz, Dz, 1,
                       0LL, 0LL, 0LL, 0LL, 0LL, 0LL, 2);
}

// Round 4
// 642.288 us; speedup vs baseline: 5.6649x; 1.2579x over previous
//
#include <hip/hip_runtime.h>
#include <hip/hip_bf16.h>
#include <math.h>

#define Bz 4
#define Sz 512
#define Dz 2048
#define NHz 8
#define DEGz 4
#define HDz 256
#define AHz 16
#define AHDz 128
#define SCALE_ATT 0.08838834764831845f  // 1/sqrt(128)

typedef __attribute__((ext_vector_type(8))) short short8;
typedef __attribute__((ext_vector_type(4))) float f32x4;

#define AS1 __attribute__((address_space(1)))
#define AS3 __attribute__((address_space(3)))

__device__ inline void gload16(const void* g, void* l) {
    __builtin_amdgcn_global_load_lds((const AS1 void*)g, (AS3 void*)l, 16, 0, 0);
}

// ---------------------------------------------------------------------------
// Multi-op GEMM/transpose dispatcher.
// GEMM op: C[m][n] = sum_k A[m][k]*BT[n][k], m97 structure (128x128, BK=32).
// flags: 1=bf16 out, 2=fp32 residual add, 4=score epilogue (scale+causal,
//        skip fully-masked tiles), 8=causal K-limit (kEnd=row0+128),
//        32=transpose+cvt op (A=fp32 src, C=bf16 dst)
struct GOp {
    const void* A; const void* B; void* C; const float* add;
    long long sAb, sAh, sBb, sBh, sCb, sCh, sKs;
    int K, lda, ldb, ldc, nbh, gx, gy, ksplit, flags, tileEnd;
};
struct GArgs { int n; GOp op[6]; };

__global__ __launch_bounds__(256) void gemm_multi(GArgs ga) {
    __shared__ unsigned short As[128 * 32];
    __shared__ unsigned short Bs[128 * 32];

    int tid = blockIdx.x;
    int oi = 0;
    while (tid >= ga.op[oi].tileEnd) ++oi;
    GOp o = ga.op[oi];
    int local = tid - (oi ? ga.op[oi - 1].tileEnd : 0);
    int t = threadIdx.x;

    if (o.flags & 32) {
        // 32x32 transpose + fp32->bf16
        const float* src = (const float*)o.A;
        __hip_bfloat16* dst = (__hip_bfloat16*)o.C;
        int ty = local / o.gx, tx = local - ty * o.gx;
        int k0 = ty * 32, n0 = tx * 32;
        float* tile = (float*)As;  // [32][33]
        int c = t & 31, r8 = t >> 5;
#pragma unroll
        for (int p = 0; p < 4; ++p)
            tile[(r8 + p * 8) * 33 + c] = src[(long long)(k0 + r8 + p * 8) * o.lda + n0 + c];
        __syncthreads();
#pragma unroll
        for (int p = 0; p < 4; ++p)
            dst[(long long)(n0 + r8 + p * 8) * o.ldc + k0 + c] =
                __float2bfloat16(tile[c * 33 + r8 + p * 8]);
        return;
    }

    int tpb = o.gx * o.gy * o.ksplit;
    int batch = local / tpb;
    int r2 = local - batch * tpb;
    int perSplit = o.gx * o.gy;
    int ks = r2 / perSplit;
    int r3 = r2 - ks * perSplit;
    int ty = r3 / o.gx;
    int tx = r3 - ty * o.gx;
    int row0 = ty * 128, col0 = tx * 128;

    if ((o.flags & 4) && (col0 > row0 + 127)) return;  // fully masked: softmax masks

    int zb = batch / o.nbh, zh = batch - zb * o.nbh;
    long long cb = (long long)zb * o.sCb + (long long)zh * o.sCh + (long long)ks * o.sKs;

    int kLen = o.K / o.ksplit;
    int kStart = ks * kLen;
    int kEnd = kStart + kLen;
    if (o.flags & 8) { int ke = row0 + 128; kEnd = kEnd < ke ? kEnd : ke; }

    const unsigned short* Ab = (const unsigned short*)o.A + zb * o.sAb + zh * o.sAh;
    const unsigned short* Bb = (const unsigned short*)o.B + zb * o.sBb + zh * o.sBh;

    int w = t >> 6, l = t & 63;
    int lrow = l >> 2;
    int lchunk = (l & 3) * 8;

    const unsigned short* aP0 = Ab + (long long)(row0 + w * 16 + lrow) * o.lda + kStart + lchunk;
    const unsigned short* aP1 = aP0 + 64LL * o.lda;
    const unsigned short* bP0 = Bb + (long long)(col0 + w * 16 + lrow) * o.ldb + kStart + lchunk;
    const unsigned short* bP1 = bP0 + 64LL * o.ldb;
    unsigned short* aL0 = As + w * 512;
    unsigned short* aL1 = As + (w + 4) * 512;
    unsigned short* bL0 = Bs + w * 512;
    unsigned short* bL1 = Bs + (w + 4) * 512;

    int lm = l & 15, lq = l >> 4;
    int wr = (w >> 1) * 64, wc = (w & 1) * 64;

    f32x4 acc[4][4];
#pragma unroll
    for (int i = 0; i < 4; ++i)
#pragma unroll
        for (int j = 0; j < 4; ++j) acc[i][j] = (f32x4){0.f, 0.f, 0.f, 0.f};

    for (int k0 = kStart; k0 < kEnd; k0 += 32) {
        gload16(aP0, aL0);
        gload16(aP1, aL1);
        gload16(bP0, bL0);
        gload16(bP1, bL1);
        aP0 += 32; aP1 += 32; bP0 += 32; bP1 += 32;
        __syncthreads();

        short8 af[4], bfr[4];
#pragma unroll
        for (int i = 0; i < 4; ++i)
            af[i] = *(const short8*)(As + (wr + i * 16 + lm) * 32 + lq * 8);
#pragma unroll
        for (int j = 0; j < 4; ++j)
            bfr[j] = *(const short8*)(Bs + (wc + j * 16 + lm) * 32 + lq * 8);
#pragma unroll
        for (int i = 0; i < 4; ++i)
#pragma unroll
            for (int j = 0; j < 4; ++j)
                acc[i][j] = __builtin_amdgcn_mfma_f32_16x16x32_bf16(af[i], bfr[j], acc[i][j], 0, 0, 0);
        __syncthreads();
    }

    if (o.flags & 1) {
        __hip_bfloat16* C = (__hip_bfloat16*)o.C;
#pragma unroll
        for (int i = 0; i < 4; ++i)
#pragma unroll
            for (int j = 0; j < 4; ++j)
#pragma unroll
                for (int r = 0; r < 4; ++r) {
                    int grow = row0 + wr + i * 16 + lq * 4 + r;
                    int gcol = col0 + wc + j * 16 + lm;
                    float v = acc[i][j][r];
                    if (o.flags & 4) v = (gcol > grow) ? -1e9f : v * SCALE_ATT;
                    C[cb + (long long)grow * o.ldc + gcol] = __float2bfloat16(v);
                }
    } else {
        float* C = (float*)o.C;
#pragma unroll
        for (int i = 0; i < 4; ++i)
#pragma unroll
            for (int j = 0; j < 4; ++j)
#pragma unroll
                for (int r = 0; r < 4; ++r) {
                    int grow = row0 + wr + i * 16 + lq * 4 + r;
                    int gcol = col0 + wc + j * 16 + lm;
                    float v = acc[i][j][r];
                    long long ci = cb + (long long)grow * o.ldc + gcol;
                    if (o.flags & 2) v += o.add[ci];
                    C[ci] = v;
                }
    }
}

// ---------------------------------------------------------------------------
// rmsnorm (fp32 in, bf16 out), one block per row
__global__ __launch_bounds__(256) void rmsnorm_kernel(const float* __restrict__ x,
                                                      const float* __restrict__ w,
                                                      __hip_bfloat16* __restrict__ out) {
    long long base = (long long)blockIdx.x * Dz;
    int t = threadIdx.x;
    float v[8];
    float ss = 0.f;
#pragma unroll
    for (int p = 0; p < 8; ++p) { v[p] = x[base + t + p * 256]; ss += v[p] * v[p]; }
    __shared__ float red[256];
    red[t] = ss; __syncthreads();
    for (int s2 = 128; s2 > 0; s2 >>= 1) { if (t < s2) red[t] += red[t + s2]; __syncthreads(); }
    float sc = rsqrtf(red[0] / (float)Dz + 1e-6f);
#pragma unroll
    for (int p = 0; p < 8; ++p) { int c = t + p * 256; out[base + c] = __float2bfloat16(v[p] * sc * w[c]); }
}

// xmean phase 1: partial sums over 64-row chunks. grid = B*8sc*8dc = 256
__global__ __launch_bounds__(256) void xmean_p1(const __hip_bfloat16* __restrict__ xn,
                                                float* __restrict__ xmp) {
    int blk = blockIdx.x;
    int b = blk >> 6, sc = (blk >> 3) & 7, dc = blk & 7;
    int t = threadIdx.x;
    int d = dc * 256 + t;
    const __hip_bfloat16* p = xn + (long long)b * Sz * Dz + (long long)sc * 64 * Dz + d;
    float s = 0.f;
    for (int si = 0; si < 64; ++si) s += __bfloat162float(p[(long long)si * Dz]);
    xmp[(b * 8 + sc) * Dz + d] = s;
}

// mlp1 with integrated mean-reduction: h[b,j]=silu(xm@wc1+bc1). grid = B*16 = 64
__global__ __launch_bounds__(256) void mlp1_kernel(const float* __restrict__ xmp,
                                                   const float* __restrict__ wc1,
                                                   const float* __restrict__ bc1,
                                                   float* __restrict__ h) {
    int blk = blockIdx.x;
    int b = blk >> 4, jb = blk & 15;
    int t = threadIdx.x;
    __shared__ float xs[Dz];
    __shared__ float red[8][32];
    const float* P = xmp + b * 8 * Dz;
#pragma unroll
    for (int p = 0; p < 8; ++p) {
        int d = t + p * 256;
        float s = 0.f;
#pragma unroll
        for (int q = 0; q < 8; ++q) s += P[q * Dz + d];
        xs[d] = s * (1.0f / (float)Sz);
    }
    __syncthreads();
    int j = jb * 32 + (t & 31), ksl = t >> 5;
    float s = 0.f;
    for (int k = ksl * 256; k < ksl * 256 + 256; ++k)
        s += xs[k] * wc1[(long long)k * 512 + j];
    red[ksl][t & 31] = s;
    __syncthreads();
    if (t < 32) {
        float tot = 0.f;
#pragma unroll
        for (int q = 0; q < 8; ++q) tot += red[q][t];
        tot += bc1[jb * 32 + t];
        h[b * 512 + jb * 32 + t] = tot / (1.0f + expf(-tot));
    }
}

// coeffs with k-split. grid = B*128 = 512
__global__ __launch_bounds__(256) void coeffs_kernel(const float* __restrict__ h,
                                                     const float* __restrict__ wc2,
                                                     const float* __restrict__ bc2,
                                                     float* __restrict__ coeffs) {
    int blk = blockIdx.x;
    int b = blk >> 7, ib = blk & 127;
    int t = threadIdx.x;
    int i = ib * 64 + (t & 63), ksl = t >> 6;
    const float* hb = h + b * 512;
    float s = 0.f;
    for (int k = ksl * 128; k < ksl * 128 + 128; ++k)
        s += hb[k] * wc2[(long long)k * 8192 + i];
    __shared__ float red[4][64];
    red[ksl][t & 63] = s;
    __syncthreads();
    if (t < 64) {
        int ii = ib * 64 + t;
        float tot = red[0][t] + red[1][t] + red[2][t] + red[3][t] + bc2[ii];
        int kdeg = (ii >> 8) & 3;
        coeffs[b * 8192 + ii] = tot * (0.1f / (float)(kdeg + 1));
    }
}

// Chebyshev path; xn bf16 in, cheby/kv bf16 out
__global__ __launch_bounds__(256) void cheby_kernel(const __hip_bfloat16* __restrict__ xn,
                                                    const float* __restrict__ coeffs,
                                                    __hip_bfloat16* __restrict__ cheby_out,
                                                    __hip_bfloat16* __restrict__ kv_src) {
    int bs = blockIdx.x;
    int b = bs >> 9;
    long long base = (long long)bs * Dz;
    int t = threadIdx.x;
    __shared__ float xrow[Dz];
    __shared__ float hsum[NHz][33];
    __shared__ float T[NHz][4];
#pragma unroll
    for (int p = 0; p < 8; ++p) xrow[t + p * 256] = __bfloat162float(xn[base + t + p * 256]);
    __syncthreads();
    int hh = t >> 5, lane = t & 31;
    float s = 0.f;
#pragma unroll
    for (int q = 0; q < 8; ++q) s += xrow[hh * HDz + lane + q * 32];
    hsum[hh][lane] = s;
    __syncthreads();
    if (t < NHz) {
        float tot = 0.f;
        for (int l2 = 0; l2 < 32; ++l2) tot += hsum[t][l2];
        float z = tanhf(tot / (float)HDz);
        float t2 = 2.f * z * z - 1.f;
        T[t][0] = 1.f; T[t][1] = z; T[t][2] = t2; T[t][3] = 2.f * z * t2 - z;
    }
    __syncthreads();
    const float* cbp = coeffs + (long long)b * (NHz * DEGz * HDz);
#pragma unroll
    for (int p = 0; p < 8; ++p) {
        int e = t + p * 256;
        int hd = e >> 8;
        int d = e & (HDz - 1);
        const float* ch = cbp + hd * (DEGz * HDz) + d;
        float co = T[hd][0] * ch[0] + T[hd][1] * ch[HDz] + T[hd][2] * ch[2 * HDz] + T[hd][3] * ch[3 * HDz];
        cheby_out[base + e] = __float2bfloat16(co);
        kv_src[base + e] = __float2bfloat16(xrow[e] + co);
    }
}

// softmax over 512-wide bf16 rows; applies causal mask itself
__global__ __launch_bounds__(128) void softmax_kernel(__hip_bfloat16* __restrict__ sc) {
    long long rid = blockIdx.x;
    int i = (int)(rid & (Sz - 1));
    long long base = rid * Sz;
    int t = threadIdx.x;
    float vals[4];
    float mx = -1e30f;
#pragma unroll
    for (int p = 0; p < 4; ++p) {
        int j = t + p * 128;
        float v = __bfloat162float(sc[base + j]);
        if (j > i) v = -1e9f;
        vals[p] = v;
        mx = fmaxf(mx, v);
    }
    __shared__ float red[128];
    red[t] = mx; __syncthreads();
    for (int s2 = 64; s2 > 0; s2 >>= 1) { if (t < s2) red[t] = fmaxf(red[t], red[t + s2]); __syncthreads(); }
    mx = red[0]; __syncthreads();
    float sum = 0.f;
#pragma unroll
    for (int p = 0; p < 4; ++p) { vals[p] = __expf(vals[p] - mx); sum += vals[p]; }
    red[t] = sum; __syncthreads();
    for (int s2 = 64; s2 > 0; s2 >>= 1) { if (t < s2) red[t] += red[t + s2]; __syncthreads(); }
    float inv = 1.0f / red[0];
#pragma unroll
    for (int p = 0; p < 4; ++p) sc[base + t + p * 128] = __float2bfloat16(vals[p] * inv);
}

// hcat = [rmsnorm(cheby,w_nc), rmsnorm(slr,w_ns)]
__global__ __launch_bounds__(256) void hcat_kernel(const __hip_bfloat16* __restrict__ cheby,
                                                   const __hip_bfloat16* __restrict__ slr,
                                                   const float* __restrict__ w_nc,
                                                   const float* __restrict__ w_ns,
                                                   __hip_bfloat16* __restrict__ hcat) {
    long long row = blockIdx.x;
    const __hip_bfloat16* c = cheby + row * Dz;
    const __hip_bfloat16* sl = slr + row * Dz;
    __hip_bfloat16* o = hcat + row * (2 * Dz);
    int t = threadIdx.x;
    float v1[8], v2[8];
    float ss1 = 0.f, ss2 = 0.f;
#pragma unroll
    for (int p = 0; p < 8; ++p) {
        v1[p] = __bfloat162float(c[t + p * 256]);  ss1 += v1[p] * v1[p];
        v2[p] = __bfloat162float(sl[t + p * 256]); ss2 += v2[p] * v2[p];
    }
    __shared__ float red[256];
    red[t] = ss1; __syncthreads();
    for (int s2 = 128; s2 > 0; s2 >>= 1) { if (t < s2) red[t] += red[t + s2]; __syncthreads(); }
    float sc1 = rsqrtf(red[0] / (float)Dz + 1e-6f);
    __syncthreads();
    red[t] = ss2; __syncthreads();
    for (int s2 = 128; s2 > 0; s2 >>= 1) { if (t < s2) red[t] += red[t + s2]; __syncthreads(); }
    float sc2 = rsqrtf(red[0] / (float)Dz + 1e-6f);
#pragma unroll
    for (int p = 0; p < 8; ++p) {
        int cx = t + p * 256;
        o[cx] = __float2bfloat16(v1[p] * sc1 * w_nc[cx]);
        o[Dz + cx] = __float2bfloat16(v2[p] * sc2 * w_ns[cx]);
    }
}

// fused = rmsnorm(silu(gate)*value, w_np) — from bf16 gv
__global__ __launch_bounds__(256) void fusedgate_kernel(const __hip_bfloat16* __restrict__ gv,
                                                        const float* __restrict__ w_np,
                                                        __hip_bfloat16* __restrict__ fused) {
    long long row = blockIdx.x;
    const __hip_bfloat16* g = gv + row * (2 * Dz);
    __hip_bfloat16* o = fused + row * Dz;
    int t = threadIdx.x;
    float f[8];
    float ss = 0.f;
#pragma unroll
    for (int p = 0; p < 8; ++p) {
        float ga = __bfloat162float(g[t + p * 256]);
        float va = __bfloat162float(g[Dz + t + p * 256]);
        float sv = ga / (1.0f + expf(-ga)) * va;
        f[p] = sv; ss += sv * sv;
    }
    __shared__ float red[256];
    red[t] = ss; __syncthreads();
    for (int s2 = 128; s2 > 0; s2 >>= 1) { if (t < s2) red[t] += red[t + s2]; __syncthreads(); }
    float sc = rsqrtf(red[0] / (float)Dz + 1e-6f);
#pragma unroll
    for (int p = 0; p < 8; ++p) { int cx = t + p * 256; o[cx] = __float2bfloat16(f[p] * sc * w_np[cx]); }
}

// fused-gate from 2 fp32 split-K partials (sums the gv reduction in-place)
__global__ __launch_bounds__(256) void fusedgate_sum_kernel(const float* __restrict__ P,
                                                            const float* __restrict__ w_np,
                                                            __hip_bfloat16* __restrict__ fused) {
    long long row = blockIdx.x;
    const float* g0 = P + row * (2 * Dz);
    const float* g1 = g0 + 2048LL * 4096;
    __hip_bfloat16* o = fused + row * Dz;
    int t = threadIdx.x;
    float f[8];
    float ss = 0.f;
#pragma unroll
    for (int p = 0; p < 8; ++p) {
        int cx = t + p * 256;
        float ga = g0[cx] + g1[cx];
        float va = g0[Dz + cx] + g1[Dz + cx];
        float sv = ga / (1.0f + expf(-ga)) * va;
        f[p] = sv; ss += sv * sv;
    }
    __shared__ float red[256];
    red[t] = ss; __syncthreads();
    for (int s2 = 128; s2 > 0; s2 >>= 1) { if (t < s2) red[t] += red[t + s2]; __syncthreads(); }
    float sc = rsqrtf(red[0] / (float)Dz + 1e-6f);
#pragma unroll
    for (int p = 0; p < 8; ++p) { int cx = t + p * 256; o[cx] = __float2bfloat16(f[p] * sc * w_np[cx]); }
}

// ---------------------------------------------------------------------------
static GOp gop(const void* A, const void* B, void* C, const float* add,
               int K, int lda, int ldb, int ldc, int nbh, int nb, int gx, int gy,
               int ksplit, long long sAb, long long sAh, long long sBb, long long sBh,
               long long sCb, long long sCh, long long sKs, int flags) {
    GOp o;
    o.A = A; o.B = B; o.C = C; o.add = add;
    o.sAb = sAb; o.sAh = sAh; o.sBb = sBb; o.sBh = sBh; o.sCb = sCb; o.sCh = sCh; o.sKs = sKs;
    o.K = K; o.lda = lda; o.ldb = ldb; o.ldc = ldc; o.nbh = nbh;
    o.gx = gx; o.gy = gy; o.ksplit = ksplit; o.flags = flags;
    o.tileEnd = (flags & 32) ? gx * gy : nb * gx * gy * ksplit;  // count; prefixed later
    return o;
}

static void launch_multi(hipStream_t st, GOp* ops, int n) {
    GArgs ga; ga.n = n;
    int acc = 0;
    for (int i = 0; i < n; ++i) { acc += ops[i].tileEnd; ga.op[i] = ops[i]; ga.op[i].tileEnd = acc; }
    hipLaunchKernelGGL(gemm_multi, dim3(acc), dim3(256), 0, st, ga);
}

extern "C" void kernel_launch(void* const* d_in, const int* in_sizes, int n_in,
                              void* d_out, int out_size, void* d_ws, size_t ws_size,
                              hipStream_t stream) {
    const float* x     = (const float*)d_in[0];
    const float* w_in  = (const float*)d_in[1];
    const float* wc1   = (const float*)d_in[6];
    const float* bc1   = (const float*)d_in[7];
    const float* wc2   = (const float*)d_in[8];
    const float* bc2   = (const float*)d_in[9];
    const float* wq    = (const float*)d_in[10];
    const float* wk    = (const float*)d_in[11];
    const float* wv    = (const float*)d_in[12];
    const float* wo    = (const float*)d_in[13];
    const float* w_nc  = (const float*)d_in[14];
    const float* w_ns  = (const float*)d_in[15];
    const float* w_fgv = (const float*)d_in[16];
    const float* w_np  = (const float*)d_in[17];
    const float* w_out = (const float*)d_in[18];
    float* out = (float*)d_out;

    const size_t MB = 1ull << 20;
    char* W = (char*)d_ws;
    __hip_bfloat16* xn_bf    = (__hip_bfloat16*)(W + 0 * MB);
    __hip_bfloat16* kv_bf    = (__hip_bfloat16*)(W + 8 * MB);
    __hip_bfloat16* cheby_bf = (__hip_bfloat16*)(W + 16 * MB);
    __hip_bfloat16* q_bf     = (__hip_bfloat16*)(W + 24 * MB);
    __hip_bfloat16* k_bf     = (__hip_bfloat16*)(W + 32 * MB);
    __hip_bfloat16* vT_bf    = (__hip_bfloat16*)(W + 40 * MB);
    __hip_bfloat16* o_bf     = (__hip_bfloat16*)(W + 48 * MB);
    __hip_bfloat16* scores   = (__hip_bfloat16*)(W + 56 * MB);   // 32MB
    __hip_bfloat16* wq_t     = (__hip_bfloat16*)(W + 88 * MB);
    __hip_bfloat16* wk_t     = (__hip_bfloat16*)(W + 96 * MB);
    __hip_bfloat16* wv_t     = (__hip_bfloat16*)(W + 104 * MB);
    __hip_bfloat16* wo_t     = (__hip_bfloat16*)(W + 112 * MB);
    __hip_bfloat16* wout_t   = (__hip_bfloat16*)(W + 120 * MB);
    // lifetime reuse (scores region becomes wfgv_t only AFTER PV has consumed it)
    __hip_bfloat16* wfgv_t   = (__hip_bfloat16*)(W + 56 * MB);
    __hip_bfloat16* slr_bf   = (__hip_bfloat16*)(W + 0 * MB);    // xn dead
    __hip_bfloat16* hcat_bf  = (__hip_bfloat16*)(W + 24 * MB);   // q,k dead (16MB)
    __hip_bfloat16* gv_bf    = (__hip_bfloat16*)(W + 40 * MB);   // vT,o dead (16MB)
    __hip_bfloat16* fused_bf = (__hip_bfloat16*)(W + 8 * MB);    // kv dead
    float* xmp   = (float*)(W + 128 * MB);                       // 8*B*D
    float* hbuf  = xmp + 65536;
    float* cbuf  = hbuf + 2048;
    float* gvP   = (float*)(W + 132 * MB);                       // 64MB split-K partials

    bool doSplit = ws_size >= 197 * MB;

    const int BS = Bz * Sz;
    const long long SD = (long long)Sz * Dz;
    const long long SS = (long long)Sz * Sz;

    // L1: five 2048x2048 weight transposes in one launch
    {
        GOp ops[5];
        const float* srcs[5] = {wq, wk, wv, wo, w_out};
        __hip_bfloat16* dsts[5] = {wq_t, wk_t, wv_t, wo_t, wout_t};
        for (int i = 0; i < 5; ++i)
            ops[i] = gop(srcs[i], nullptr, dsts[i], nullptr, Dz, Dz, 0, Dz,
                         1, 1, 64, 64, 1, 0, 0, 0, 0, 0, 0, 0, 32);
        launch_multi(stream, ops, 5);
    }
    // L2: xn = rmsnorm(x)
    hipLaunchKernelGGL(rmsnorm_kernel, dim3(BS), dim3(256), 0, stream, x, w_in, xn_bf);
    // L3-L5: coeff path
    hipLaunchKernelGGL(xmean_p1, dim3(256), dim3(256), 0, stream, xn_bf, xmp);
    hipLaunchKernelGGL(mlp1_kernel, dim3(64), dim3(256), 0, stream, xmp, wc1, bc1, hbuf);
    hipLaunchKernelGGL(coeffs_kernel, dim3(512), dim3(256), 0, stream, hbuf, wc2, bc2, cbuf);
    // L6: cheby + kv_src
    hipLaunchKernelGGL(cheby_kernel, dim3(BS), dim3(256), 0, stream, xn_bf, cbuf, cheby_bf, kv_bf);
    // L7: q, k, vT in one launch (768 tiles)
    {
        GOp ops[3];
        ops[0] = gop(xn_bf, wq_t, q_bf, nullptr, Dz, Dz, Dz, Dz, 1, 1, 16, 16, 1,
                     0, 0, 0, 0, 0, 0, 0, 1);
        ops[1] = gop(kv_bf, wk_t, k_bf, nullptr, Dz, Dz, Dz, Dz, 1, 1, 16, 16, 1,
                     0, 0, 0, 0, 0, 0, 0, 1);
        ops[2] = gop(wv_t, kv_bf, vT_bf, nullptr, Dz, Dz, Dz, Sz, 1, Bz, 4, 16, 1,
                     0, 0, SD, 0, (long long)Dz * Sz, 0, 0, 1);
        launch_multi(stream, ops, 3);
    }
    // L8: scores = q@k^T, scale+mask epilogue, skip masked tiles
    {
        GOp op = gop(q_bf, k_bf, scores, nullptr, AHDz, Dz, Dz, Sz, AHz, Bz * AHz, 4, 4, 1,
                     SD, AHDz, SD, AHDz, (long long)AHz * SS, SS, 0, 1 | 4);
        launch_multi(stream, &op, 1);
    }
    // L9: softmax (applies causal mask)
    hipLaunchKernelGGL(softmax_kernel, dim3(Bz * AHz * Sz), dim3(128), 0, stream, scores);
    // L10: PV alone (reads scores — nothing may write the scores region here!)
    {
        GOp op = gop(scores, vT_bf, o_bf, nullptr, Sz, Sz, Sz, Dz, AHz, Bz * AHz, 1, 4, 1,
                     (long long)AHz * SS, SS, (long long)Dz * Sz, 128LL * Sz,
                     SD, 128, 0, 1 | 8);
        launch_multi(stream, &op, 1);
    }
    // L11: slr = o @ wo  +  wfgv transpose into now-dead scores region
    {
        GOp ops[2];
        ops[0] = gop(o_bf, wo_t, slr_bf, nullptr, Dz, Dz, Dz, Dz, 1, 1, 16, 16, 1,
                     0, 0, 0, 0, 0, 0, 0, 1);
        ops[1] = gop(w_fgv, nullptr, wfgv_t, nullptr, 2 * Dz, 2 * Dz, 0, 2 * Dz,
                     1, 1, 128, 128, 1, 0, 0, 0, 0, 0, 0, 0, 32);
        launch_multi(stream, ops, 2);
    }
    // L12: hcat
    hipLaunchKernelGGL(hcat_kernel, dim3(BS), dim3(256), 0, stream, cheby_bf, slr_bf, w_nc, w_ns, hcat_bf);
    // L13: gv = hcat @ w_fgv  (split-K=2 into fp32 partials when ws allows)
    if (doSplit) {
        GOp op = gop(hcat_bf, wfgv_t, gvP, nullptr, 2 * Dz, 2 * Dz, 2 * Dz, 2 * Dz,
                     1, 1, 32, 16, 2, 0, 0, 0, 0, 0, 0, 2048LL * 4096, 0);
        launch_multi(stream, &op, 1);
        hipLaunchKernelGGL(fusedgate_sum_kernel, dim3(BS), dim3(256), 0, stream, gvP, w_np, fused_bf);
    } else {
        GOp op = gop(hcat_bf, wfgv_t, gv_bf, nullptr, 2 * Dz, 2 * Dz, 2 * Dz, 2 * Dz,
                     1, 1, 32, 16, 1, 0, 0, 0, 0, 0, 0, 0, 1);
        launch_multi(stream, &op, 1);
        hipLaunchKernelGGL(fusedgate_kernel, dim3(BS), dim3(256), 0, stream, gv_bf, w_np, fused_bf);
    }
    // L15: out = x + fused @ w_out
    {
        GOp op = gop(fused_bf, wout_t, out, x, Dz, Dz, Dz, Dz, 1, 1, 16, 16, 1,
                     0, 0, 0, 0, 0, 0, 0, 2);
        launch_multi(stream, &op, 1);
    }
}

// Round 5
// 621.193 us; speedup vs baseline: 5.8573x; 1.0340x over previous
//
#include <hip/hip_runtime.h>
#include <hip/hip_bf16.h>
#include <math.h>

#define Bz 4
#define Sz 512
#define Dz 2048
#define NHz 8
#define DEGz 4
#define HDz 256
#define AHz 16
#define AHDz 128
#define SCALE_ATT 0.08838834764831845f  // 1/sqrt(128)

typedef __attribute__((ext_vector_type(8))) short short8;
typedef __attribute__((ext_vector_type(4))) float f32x4;

#define AS1 __attribute__((address_space(1)))
#define AS3 __attribute__((address_space(3)))

__device__ inline void gload16(const void* g, void* l) {
    __builtin_amdgcn_global_load_lds((const AS1 void*)g, (AS3 void*)l, 16, 0, 0);
}

// ---------------------------------------------------------------------------
// Multi-op GEMM/transpose dispatcher.
// GEMM op: C[m][n] = sum_k A[m][k]*BT[n][k]. 128x128 tile, BK=64 staged as
// two BK=32 sub-tiles per barrier (32 MFMAs/barrier-pair; keeps the m97
// conflict-benign LDS layout since global_load_lds forbids padding).
// flags: 1=bf16 out, 2=fp32 residual add, 4=score epilogue (scale+causal,
//        skip fully-masked tiles), 8=causal K-limit (kEnd=row0+128),
//        32=transpose+cvt op (A=fp32 src, C=bf16 dst)
struct GOp {
    const void* A; const void* B; void* C; const float* add;
    long long sAb, sAh, sBb, sBh, sCb, sCh;
    int K, lda, ldb, ldc, nbh, gx, gy, flags, tileEnd;
};
struct GArgs { int n; GOp op[6]; };

__global__ __launch_bounds__(256) void gemm_multi(GArgs ga) {
    // two BK=32 sub-tiles for A and B: 4096 shorts each sub-tile
    __shared__ unsigned short As[2 * 128 * 32];
    __shared__ unsigned short Bs[2 * 128 * 32];

    int tid = blockIdx.x;
    int oi = 0;
    while (tid >= ga.op[oi].tileEnd) ++oi;
    GOp o = ga.op[oi];
    int local = tid - (oi ? ga.op[oi - 1].tileEnd : 0);
    int t = threadIdx.x;

    if (o.flags & 32) {
        // 32x32 transpose + fp32->bf16
        const float* src = (const float*)o.A;
        __hip_bfloat16* dst = (__hip_bfloat16*)o.C;
        int ty = local / o.gx, tx = local - ty * o.gx;
        int k0 = ty * 32, n0 = tx * 32;
        float* tile = (float*)As;  // [32][33]
        int c = t & 31, r8 = t >> 5;
#pragma unroll
        for (int p = 0; p < 4; ++p)
            tile[(r8 + p * 8) * 33 + c] = src[(long long)(k0 + r8 + p * 8) * o.lda + n0 + c];
        __syncthreads();
#pragma unroll
        for (int p = 0; p < 4; ++p)
            dst[(long long)(n0 + r8 + p * 8) * o.ldc + k0 + c] =
                __float2bfloat16(tile[c * 33 + r8 + p * 8]);
        return;
    }

    int perOp = o.gx * o.gy;
    int batch = local / perOp;
    int r3 = local - batch * perOp;
    int ty = r3 / o.gx;
    int tx = r3 - ty * o.gx;
    int row0 = ty * 128, col0 = tx * 128;

    if ((o.flags & 4) && (col0 > row0 + 127)) return;  // fully masked: softmax masks

    int zb = batch / o.nbh, zh = batch - zb * o.nbh;
    long long cb = (long long)zb * o.sCb + (long long)zh * o.sCh;

    int kEnd = o.K;
    if (o.flags & 8) { int ke = row0 + 128; kEnd = kEnd < ke ? kEnd : ke; }

    const unsigned short* Ab = (const unsigned short*)o.A + zb * o.sAb + zh * o.sAh;
    const unsigned short* Bb = (const unsigned short*)o.B + zb * o.sBb + zh * o.sBh;

    int w = t >> 6, l = t & 63;
    int lrow = l >> 2;            // row within 16-row segment
    int lchunk = (l & 3) * 8;     // k-element offset of 8-elem chunk

    const unsigned short* aP0 = Ab + (long long)(row0 + w * 16 + lrow) * o.lda + lchunk;
    const unsigned short* aP1 = aP0 + 64LL * o.lda;
    const unsigned short* bP0 = Bb + (long long)(col0 + w * 16 + lrow) * o.ldb + lchunk;
    const unsigned short* bP1 = bP0 + 64LL * o.ldb;
    unsigned short* aL0 = As + w * 512;
    unsigned short* aL1 = As + (w + 4) * 512;
    unsigned short* bL0 = Bs + w * 512;
    unsigned short* bL1 = Bs + (w + 4) * 512;

    int lm = l & 15, lq = l >> 4;
    int wr = (w >> 1) * 64, wc = (w & 1) * 64;

    f32x4 acc[4][4];
#pragma unroll
    for (int i = 0; i < 4; ++i)
#pragma unroll
        for (int j = 0; j < 4; ++j) acc[i][j] = (f32x4){0.f, 0.f, 0.f, 0.f};

    for (int k0 = 0; k0 < kEnd; k0 += 64) {
        // stage sub-tile 0 (k0..k0+31) and sub-tile 1 (k0+32..k0+63)
        gload16(aP0, aL0);
        gload16(aP1, aL1);
        gload16(bP0, bL0);
        gload16(bP1, bL1);
        gload16(aP0 + 32, aL0 + 4096);
        gload16(aP1 + 32, aL1 + 4096);
        gload16(bP0 + 32, bL0 + 4096);
        gload16(bP1 + 32, bL1 + 4096);
        aP0 += 64; aP1 += 64; bP0 += 64; bP1 += 64;
        __syncthreads();

#pragma unroll
        for (int h = 0; h < 2; ++h) {
            const unsigned short* Ah = As + h * 4096;
            const unsigned short* Bh = Bs + h * 4096;
            short8 af[4], bfr[4];
#pragma unroll
            for (int i = 0; i < 4; ++i)
                af[i] = *(const short8*)(Ah + (wr + i * 16 + lm) * 32 + lq * 8);
#pragma unroll
            for (int j = 0; j < 4; ++j)
                bfr[j] = *(const short8*)(Bh + (wc + j * 16 + lm) * 32 + lq * 8);
#pragma unroll
            for (int i = 0; i < 4; ++i)
#pragma unroll
                for (int j = 0; j < 4; ++j)
                    acc[i][j] = __builtin_amdgcn_mfma_f32_16x16x32_bf16(af[i], bfr[j], acc[i][j], 0, 0, 0);
        }
        __syncthreads();
    }

    if (o.flags & 1) {
        __hip_bfloat16* C = (__hip_bfloat16*)o.C;
#pragma unroll
        for (int i = 0; i < 4; ++i)
#pragma unroll
            for (int j = 0; j < 4; ++j)
#pragma unroll
                for (int r = 0; r < 4; ++r) {
                    int grow = row0 + wr + i * 16 + lq * 4 + r;
                    int gcol = col0 + wc + j * 16 + lm;
                    float v = acc[i][j][r];
                    if (o.flags & 4) v = (gcol > grow) ? -1e9f : v * SCALE_ATT;
                    C[cb + (long long)grow * o.ldc + gcol] = __float2bfloat16(v);
                }
    } else {
        float* C = (float*)o.C;
#pragma unroll
        for (int i = 0; i < 4; ++i)
#pragma unroll
            for (int j = 0; j < 4; ++j)
#pragma unroll
                for (int r = 0; r < 4; ++r) {
                    int grow = row0 + wr + i * 16 + lq * 4 + r;
                    int gcol = col0 + wc + j * 16 + lm;
                    float v = acc[i][j][r];
                    long long ci = cb + (long long)grow * o.ldc + gcol;
                    if (o.flags & 2) v += o.add[ci];
                    C[ci] = v;
                }
    }
}

// ---------------------------------------------------------------------------
// rmsnorm (fp32 in, bf16 out), one block per row
__global__ __launch_bounds__(256) void rmsnorm_kernel(const float* __restrict__ x,
                                                      const float* __restrict__ w,
                                                      __hip_bfloat16* __restrict__ out) {
    long long base = (long long)blockIdx.x * Dz;
    int t = threadIdx.x;
    float v[8];
    float ss = 0.f;
#pragma unroll
    for (int p = 0; p < 8; ++p) { v[p] = x[base + t + p * 256]; ss += v[p] * v[p]; }
    __shared__ float red[256];
    red[t] = ss; __syncthreads();
    for (int s2 = 128; s2 > 0; s2 >>= 1) { if (t < s2) red[t] += red[t + s2]; __syncthreads(); }
    float sc = rsqrtf(red[0] / (float)Dz + 1e-6f);
#pragma unroll
    for (int p = 0; p < 8; ++p) { int c = t + p * 256; out[base + c] = __float2bfloat16(v[p] * sc * w[c]); }
}

// xmean phase 1: partial sums over 64-row chunks. grid = B*8sc*8dc = 256
__global__ __launch_bounds__(256) void xmean_p1(const __hip_bfloat16* __restrict__ xn,
                                                float* __restrict__ xmp) {
    int blk = blockIdx.x;
    int b = blk >> 6, sc = (blk >> 3) & 7, dc = blk & 7;
    int t = threadIdx.x;
    int d = dc * 256 + t;
    const __hip_bfloat16* p = xn + (long long)b * Sz * Dz + (long long)sc * 64 * Dz + d;
    float s = 0.f;
    for (int si = 0; si < 64; ++si) s += __bfloat162float(p[(long long)si * Dz]);
    xmp[(b * 8 + sc) * Dz + d] = s;
}

// mlp1 with integrated mean-reduction: h[b,j]=silu(xm@wc1+bc1). grid = B*16 = 64
__global__ __launch_bounds__(256) void mlp1_kernel(const float* __restrict__ xmp,
                                                   const float* __restrict__ wc1,
                                                   const float* __restrict__ bc1,
                                                   float* __restrict__ h) {
    int blk = blockIdx.x;
    int b = blk >> 4, jb = blk & 15;
    int t = threadIdx.x;
    __shared__ float xs[Dz];
    __shared__ float red[8][32];
    const float* P = xmp + b * 8 * Dz;
#pragma unroll
    for (int p = 0; p < 8; ++p) {
        int d = t + p * 256;
        float s = 0.f;
#pragma unroll
        for (int q = 0; q < 8; ++q) s += P[q * Dz + d];
        xs[d] = s * (1.0f / (float)Sz);
    }
    __syncthreads();
    int j = jb * 32 + (t & 31), ksl = t >> 5;
    float s = 0.f;
    for (int k = ksl * 256; k < ksl * 256 + 256; ++k)
        s += xs[k] * wc1[(long long)k * 512 + j];
    red[ksl][t & 31] = s;
    __syncthreads();
    if (t < 32) {
        float tot = 0.f;
#pragma unroll
        for (int q = 0; q < 8; ++q) tot += red[q][t];
        tot += bc1[jb * 32 + t];
        h[b * 512 + jb * 32 + t] = tot / (1.0f + expf(-tot));
    }
}

// coeffs with k-split. grid = B*128 = 512
__global__ __launch_bounds__(256) void coeffs_kernel(const float* __restrict__ h,
                                                     const float* __restrict__ wc2,
                                                     const float* __restrict__ bc2,
                                                     float* __restrict__ coeffs) {
    int blk = blockIdx.x;
    int b = blk >> 7, ib = blk & 127;
    int t = threadIdx.x;
    int i = ib * 64 + (t & 63), ksl = t >> 6;
    const float* hb = h + b * 512;
    float s = 0.f;
    for (int k = ksl * 128; k < ksl * 128 + 128; ++k)
        s += hb[k] * wc2[(long long)k * 8192 + i];
    __shared__ float red[4][64];
    red[ksl][t & 63] = s;
    __syncthreads();
    if (t < 64) {
        int ii = ib * 64 + t;
        float tot = red[0][t] + red[1][t] + red[2][t] + red[3][t] + bc2[ii];
        int kdeg = (ii >> 8) & 3;
        coeffs[b * 8192 + ii] = tot * (0.1f / (float)(kdeg + 1));
    }
}

// Chebyshev path; xn bf16 in, cheby/kv bf16 out
__global__ __launch_bounds__(256) void cheby_kernel(const __hip_bfloat16* __restrict__ xn,
                                                    const float* __restrict__ coeffs,
                                                    __hip_bfloat16* __restrict__ cheby_out,
                                                    __hip_bfloat16* __restrict__ kv_src) {
    int bs = blockIdx.x;
    int b = bs >> 9;
    long long base = (long long)bs * Dz;
    int t = threadIdx.x;
    __shared__ float xrow[Dz];
    __shared__ float hsum[NHz][33];
    __shared__ float T[NHz][4];
#pragma unroll
    for (int p = 0; p < 8; ++p) xrow[t + p * 256] = __bfloat162float(xn[base + t + p * 256]);
    __syncthreads();
    int hh = t >> 5, lane = t & 31;
    float s = 0.f;
#pragma unroll
    for (int q = 0; q < 8; ++q) s += xrow[hh * HDz + lane + q * 32];
    hsum[hh][lane] = s;
    __syncthreads();
    if (t < NHz) {
        float tot = 0.f;
        for (int l2 = 0; l2 < 32; ++l2) tot += hsum[t][l2];
        float z = tanhf(tot / (float)HDz);
        float t2 = 2.f * z * z - 1.f;
        T[t][0] = 1.f; T[t][1] = z; T[t][2] = t2; T[t][3] = 2.f * z * t2 - z;
    }
    __syncthreads();
    const float* cbp = coeffs + (long long)b * (NHz * DEGz * HDz);
#pragma unroll
    for (int p = 0; p < 8; ++p) {
        int e = t + p * 256;
        int hd = e >> 8;
        int d = e & (HDz - 1);
        const float* ch = cbp + hd * (DEGz * HDz) + d;
        float co = T[hd][0] * ch[0] + T[hd][1] * ch[HDz] + T[hd][2] * ch[2 * HDz] + T[hd][3] * ch[3 * HDz];
        cheby_out[base + e] = __float2bfloat16(co);
        kv_src[base + e] = __float2bfloat16(xrow[e] + co);
    }
}

// softmax over 512-wide bf16 rows; applies causal mask itself
__global__ __launch_bounds__(128) void softmax_kernel(__hip_bfloat16* __restrict__ sc) {
    long long rid = blockIdx.x;
    int i = (int)(rid & (Sz - 1));
    long long base = rid * Sz;
    int t = threadIdx.x;
    float vals[4];
    float mx = -1e30f;
#pragma unroll
    for (int p = 0; p < 4; ++p) {
        int j = t + p * 128;
        float v = __bfloat162float(sc[base + j]);
        if (j > i) v = -1e9f;
        vals[p] = v;
        mx = fmaxf(mx, v);
    }
    __shared__ float red[128];
    red[t] = mx; __syncthreads();
    for (int s2 = 64; s2 > 0; s2 >>= 1) { if (t < s2) red[t] = fmaxf(red[t], red[t + s2]); __syncthreads(); }
    mx = red[0]; __syncthreads();
    float sum = 0.f;
#pragma unroll
    for (int p = 0; p < 4; ++p) { vals[p] = __expf(vals[p] - mx); sum += vals[p]; }
    red[t] = sum; __syncthreads();
    for (int s2 = 64; s2 > 0; s2 >>= 1) { if (t < s2) red[t] += red[t + s2]; __syncthreads(); }
    float inv = 1.0f / red[0];
#pragma unroll
    for (int p = 0; p < 4; ++p) sc[base + t + p * 128] = __float2bfloat16(vals[p] * inv);
}

// hcat = [rmsnorm(cheby,w_nc), rmsnorm(slr,w_ns)]
__global__ __launch_bounds__(256) void hcat_kernel(const __hip_bfloat16* __restrict__ cheby,
                                                   const __hip_bfloat16* __restrict__ slr,
                                                   const float* __restrict__ w_nc,
                                                   const float* __restrict__ w_ns,
                                                   __hip_bfloat16* __restrict__ hcat) {
    long long row = blockIdx.x;
    const __hip_bfloat16* c = cheby + row * Dz;
    const __hip_bfloat16* sl = slr + row * Dz;
    __hip_bfloat16* o = hcat + row * (2 * Dz);
    int t = threadIdx.x;
    float v1[8], v2[8];
    float ss1 = 0.f, ss2 = 0.f;
#pragma unroll
    for (int p = 0; p < 8; ++p) {
        v1[p] = __bfloat162float(c[t + p * 256]);  ss1 += v1[p] * v1[p];
        v2[p] = __bfloat162float(sl[t + p * 256]); ss2 += v2[p] * v2[p];
    }
    __shared__ float red[256];
    red[t] = ss1; __syncthreads();
    for (int s2 = 128; s2 > 0; s2 >>= 1) { if (t < s2) red[t] += red[t + s2]; __syncthreads(); }
    float sc1 = rsqrtf(red[0] / (float)Dz + 1e-6f);
    __syncthreads();
    red[t] = ss2; __syncthreads();
    for (int s2 = 128; s2 > 0; s2 >>= 1) { if (t < s2) red[t] += red[t + s2]; __syncthreads(); }
    float sc2 = rsqrtf(red[0] / (float)Dz + 1e-6f);
#pragma unroll
    for (int p = 0; p < 8; ++p) {
        int cx = t + p * 256;
        o[cx] = __float2bfloat16(v1[p] * sc1 * w_nc[cx]);
        o[Dz + cx] = __float2bfloat16(v2[p] * sc2 * w_ns[cx]);
    }
}

// fused = rmsnorm(silu(gate)*value, w_np) — from bf16 gv
__global__ __launch_bounds__(256) void fusedgate_kernel(const __hip_bfloat16* __restrict__ gv,
                                                        const float* __restrict__ w_np,
                                                        __hip_bfloat16* __restrict__ fused) {
    long long row = blockIdx.x;
    const __hip_bfloat16* g = gv + row * (2 * Dz);
    __hip_bfloat16* o = fused + row * Dz;
    int t = threadIdx.x;
    float f[8];
    float ss = 0.f;
#pragma unroll
    for (int p = 0; p < 8; ++p) {
        float ga = __bfloat162float(g[t + p * 256]);
        float va = __bfloat162float(g[Dz + t + p * 256]);
        float sv = ga / (1.0f + expf(-ga)) * va;
        f[p] = sv; ss += sv * sv;
    }
    __shared__ float red[256];
    red[t] = ss; __syncthreads();
    for (int s2 = 128; s2 > 0; s2 >>= 1) { if (t < s2) red[t] += red[t + s2]; __syncthreads(); }
    float sc = rsqrtf(red[0] / (float)Dz + 1e-6f);
#pragma unroll
    for (int p = 0; p < 8; ++p) { int cx = t + p * 256; o[cx] = __float2bfloat16(f[p] * sc * w_np[cx]); }
}

// ---------------------------------------------------------------------------
static GOp gop(const void* A, const void* B, void* C, const float* add,
               int K, int lda, int ldb, int ldc, int nbh, int nb, int gx, int gy,
               long long sAb, long long sAh, long long sBb, long long sBh,
               long long sCb, long long sCh, int flags) {
    GOp o;
    o.A = A; o.B = B; o.C = C; o.add = add;
    o.sAb = sAb; o.sAh = sAh; o.sBb = sBb; o.sBh = sBh; o.sCb = sCb; o.sCh = sCh;
    o.K = K; o.lda = lda; o.ldb = ldb; o.ldc = ldc; o.nbh = nbh;
    o.gx = gx; o.gy = gy; o.flags = flags;
    o.tileEnd = (flags & 32) ? gx * gy : nb * gx * gy;  // count; prefixed later
    return o;
}

static void launch_multi(hipStream_t st, GOp* ops, int n) {
    GArgs ga; ga.n = n;
    int acc = 0;
    for (int i = 0; i < n; ++i) { acc += ops[i].tileEnd; ga.op[i] = ops[i]; ga.op[i].tileEnd = acc; }
    hipLaunchKernelGGL(gemm_multi, dim3(acc), dim3(256), 0, st, ga);
}

extern "C" void kernel_launch(void* const* d_in, const int* in_sizes, int n_in,
                              void* d_out, int out_size, void* d_ws, size_t ws_size,
                              hipStream_t stream) {
    const float* x     = (const float*)d_in[0];
    const float* w_in  = (const float*)d_in[1];
    const float* wc1   = (const float*)d_in[6];
    const float* bc1   = (const float*)d_in[7];
    const float* wc2   = (const float*)d_in[8];
    const float* bc2   = (const float*)d_in[9];
    const float* wq    = (const float*)d_in[10];
    const float* wk    = (const float*)d_in[11];
    const float* wv    = (const float*)d_in[12];
    const float* wo    = (const float*)d_in[13];
    const float* w_nc  = (const float*)d_in[14];
    const float* w_ns  = (const float*)d_in[15];
    const float* w_fgv = (const float*)d_in[16];
    const float* w_np  = (const float*)d_in[17];
    const float* w_out = (const float*)d_in[18];
    float* out = (float*)d_out;

    const size_t MB = 1ull << 20;
    char* W = (char*)d_ws;
    __hip_bfloat16* xn_bf    = (__hip_bfloat16*)(W + 0 * MB);
    __hip_bfloat16* kv_bf    = (__hip_bfloat16*)(W + 8 * MB);
    __hip_bfloat16* cheby_bf = (__hip_bfloat16*)(W + 16 * MB);
    __hip_bfloat16* q_bf     = (__hip_bfloat16*)(W + 24 * MB);
    __hip_bfloat16* k_bf     = (__hip_bfloat16*)(W + 32 * MB);
    __hip_bfloat16* vT_bf    = (__hip_bfloat16*)(W + 40 * MB);
    __hip_bfloat16* o_bf     = (__hip_bfloat16*)(W + 48 * MB);
    __hip_bfloat16* scores   = (__hip_bfloat16*)(W + 56 * MB);   // 32MB
    __hip_bfloat16* wq_t     = (__hip_bfloat16*)(W + 88 * MB);
    __hip_bfloat16* wk_t     = (__hip_bfloat16*)(W + 96 * MB);
    __hip_bfloat16* wv_t     = (__hip_bfloat16*)(W + 104 * MB);
    __hip_bfloat16* wo_t     = (__hip_bfloat16*)(W + 112 * MB);
    __hip_bfloat16* wout_t   = (__hip_bfloat16*)(W + 120 * MB);
    // lifetime reuse (scores region becomes wfgv_t only AFTER PV has consumed it)
    __hip_bfloat16* wfgv_t   = (__hip_bfloat16*)(W + 56 * MB);
    __hip_bfloat16* slr_bf   = (__hip_bfloat16*)(W + 0 * MB);    // xn dead
    __hip_bfloat16* hcat_bf  = (__hip_bfloat16*)(W + 24 * MB);   // q,k dead (16MB)
    __hip_bfloat16* gv_bf    = (__hip_bfloat16*)(W + 40 * MB);   // vT,o dead (16MB)
    __hip_bfloat16* fused_bf = (__hip_bfloat16*)(W + 8 * MB);    // kv dead
    float* xmp   = (float*)(W + 128 * MB);                       // 8*B*D
    float* hbuf  = xmp + 65536;
    float* cbuf  = hbuf + 2048;

    const int BS = Bz * Sz;
    const long long SD = (long long)Sz * Dz;
    const long long SS = (long long)Sz * Sz;

    // L1: five 2048x2048 weight transposes in one launch
    {
        GOp ops[5];
        const float* srcs[5] = {wq, wk, wv, wo, w_out};
        __hip_bfloat16* dsts[5] = {wq_t, wk_t, wv_t, wo_t, wout_t};
        for (int i = 0; i < 5; ++i)
            ops[i] = gop(srcs[i], nullptr, dsts[i], nullptr, Dz, Dz, 0, Dz,
                         1, 1, 64, 64, 0, 0, 0, 0, 0, 0, 32);
        launch_multi(stream, ops, 5);
    }
    // L2: xn = rmsnorm(x)
    hipLaunchKernelGGL(rmsnorm_kernel, dim3(BS), dim3(256), 0, stream, x, w_in, xn_bf);
    // L3-L5: coeff path
    hipLaunchKernelGGL(xmean_p1, dim3(256), dim3(256), 0, stream, xn_bf, xmp);
    hipLaunchKernelGGL(mlp1_kernel, dim3(64), dim3(256), 0, stream, xmp, wc1, bc1, hbuf);
    hipLaunchKernelGGL(coeffs_kernel, dim3(512), dim3(256), 0, stream, hbuf, wc2, bc2, cbuf);
    // L6: cheby + kv_src
    hipLaunchKernelGGL(cheby_kernel, dim3(BS), dim3(256), 0, stream, xn_bf, cbuf, cheby_bf, kv_bf);
    // L7: q, k, vT in one launch (768 tiles)
    {
        GOp ops[3];
        ops[0] = gop(xn_bf, wq_t, q_bf, nullptr, Dz, Dz, Dz, Dz, 1, 1, 16, 16,
                     0, 0, 0, 0, 0, 0, 1);
        ops[1] = gop(kv_bf, wk_t, k_bf, nullptr, Dz, Dz, Dz, Dz, 1, 1, 16, 16,
                     0, 0, 0, 0, 0, 0, 1);
        ops[2] = gop(wv_t, kv_bf, vT_bf, nullptr, Dz, Dz, Dz, Sz, 1, Bz, 4, 16,
                     0, 0, SD, 0, (long long)Dz * Sz, 0, 1);
        launch_multi(stream, ops, 3);
    }
    // L8: scores = q@k^T, scale+mask epilogue, skip masked tiles
    {
        GOp op = gop(q_bf, k_bf, scores, nullptr, AHDz, Dz, Dz, Sz, AHz, Bz * AHz, 4, 4,
                     SD, AHDz, SD, AHDz, (long long)AHz * SS, SS, 1 | 4);
        launch_multi(stream, &op, 1);
    }
    // L9: softmax (applies causal mask)
    hipLaunchKernelGGL(softmax_kernel, dim3(Bz * AHz * Sz), dim3(128), 0, stream, scores);
    // L10: PV alone (reads scores — nothing may write the scores region here!)
    {
        GOp op = gop(scores, vT_bf, o_bf, nullptr, Sz, Sz, Sz, Dz, AHz, Bz * AHz, 1, 4,
                     (long long)AHz * SS, SS, (long long)Dz * Sz, 128LL * Sz,
                     SD, 128, 1 | 8);
        launch_multi(stream, &op, 1);
    }
    // L11: slr = o @ wo  +  wfgv transpose into now-dead scores region
    {
        GOp ops[2];
        ops[0] = gop(o_bf, wo_t, slr_bf, nullptr, Dz, Dz, Dz, Dz, 1, 1, 16, 16,
                     0, 0, 0, 0, 0, 0, 1);
        ops[1] = gop(w_fgv, nullptr, wfgv_t, nullptr, 2 * Dz, 2 * Dz, 0, 2 * Dz,
                     1, 1, 128, 128, 0, 0, 0, 0, 0, 0, 32);
        launch_multi(stream, ops, 2);
    }
    // L12: hcat
    hipLaunchKernelGGL(hcat_kernel, dim3(BS), dim3(256), 0, stream, cheby_bf, slr_bf, w_nc, w_ns, hcat_bf);
    // L13: gv = hcat @ w_fgv (single GEMM; split-K reverted — partial traffic cost > occupancy gain)
    {
        GOp op = gop(hcat_bf, wfgv_t, gv_bf, nullptr, 2 * Dz, 2 * Dz, 2 * Dz, 2 * Dz,
                     1, 1, 32, 16, 0, 0, 0, 0, 0, 0, 1);
        launch_multi(stream, &op, 1);
    }
    // L14: fused gate
    hipLaunchKernelGGL(fusedgate_kernel, dim3(BS), dim3(256), 0, stream, gv_bf, w_np, fused_bf);
    // L15: out = x + fused @ w_out
    {
        GOp op = gop(fused_bf, wout_t, out, x, Dz, Dz, Dz, Dz, 1, 1, 16, 16,
                     0, 0, 0, 0, 0, 0, 2);
        launch_multi(stream, &op, 1);
    }
}